// Round 10
// baseline (784.958 us; speedup 1.0000x reference)
//
#include <hip/hip_runtime.h>
#include <math.h>

#define N_NODES 50000
#define N_EDGES 800000
#define FDIM 128
#define KCLS 10

typedef float v2f __attribute__((ext_vector_type(2)));

__device__ __forceinline__ v2f pksplat(float a) { v2f r; r.x = a; r.y = a; return r; }
__device__ __forceinline__ v2f pkfma(v2f a, v2f b, v2f c) { return __builtin_elementwise_fma(a, b, c); }
__device__ __forceinline__ v2f pklrelu(v2f v) {
    v2f z = pksplat(0.f);
    v2f mx = __builtin_elementwise_max(v, z);
    v2f mn = __builtin_elementwise_min(v, z);
    return pkfma(pksplat(0.2f), mn, mx);
}
__device__ __forceinline__ int rfl(int v) { return __builtin_amdgcn_readfirstlane(v); }

// ---------------- CSR build ----------------

__global__ void k_count(const int* __restrict__ dst, int* __restrict__ indeg, int e_total) {
    int e = blockIdx.x * 256 + threadIdx.x;
    if (e < e_total) atomicAdd(&indeg[dst[e]], 1);
}

__global__ __launch_bounds__(1024) void k_scan_block(const int* __restrict__ in, int* __restrict__ excl,
                                                     int* __restrict__ bsum, int n) {
    __shared__ int sh[1024];
    int t = threadIdx.x;
    int g = blockIdx.x * 1024 + t;
    int v = (g < n) ? in[g] : 0;
    sh[t] = v;
    __syncthreads();
    for (int d = 1; d < 1024; d <<= 1) {
        int x = (t >= d) ? sh[t - d] : 0;
        __syncthreads();
        sh[t] += x;
        __syncthreads();
    }
    if (g < n) excl[g] = sh[t] - v;
    if (t == 1023) bsum[blockIdx.x] = sh[t];
}

__global__ void k_scan_small(int* bsum, int nb) {
    if (threadIdx.x == 0 && blockIdx.x == 0) {
        int run = 0;
        for (int i = 0; i < nb; i++) { int v = bsum[i]; bsum[i] = run; run += v; }
    }
}

__global__ __launch_bounds__(1024) void k_scan_add(int* __restrict__ offs, const int* __restrict__ bsum,
                                                   int* __restrict__ cursor, int n, int e_total) {
    int g = blockIdx.x * 1024 + threadIdx.x;
    if (g < n) {
        int v = offs[g] + bsum[blockIdx.x];
        offs[g] = v;
        cursor[g] = v;
    }
    if (g == 0) offs[n] = e_total;
}

// scatter edges into CSR order; fused: also permute edge_attr rows into sea
__global__ void k_scatter_fused(const int* __restrict__ src, const int* __restrict__ dst,
                                const float* __restrict__ edge_attr,
                                int* __restrict__ cursor, int* __restrict__ ssrc,
                                float* __restrict__ sea, int e_total) {
    int e = blockIdx.x * 256 + threadIdx.x;
    if (e < e_total) {
        int d = dst[e];
        int p = atomicAdd(&cursor[d], 1);
        ssrc[p] = src[e];
        const float4* ea = (const float4*)&edge_attr[(size_t)e * 16];
        float4* out = (float4*)&sea[(size_t)p * 16];
        float4 a = ea[0], b = ea[1], c = ea[2], q = ea[3];
        out[0] = a; out[1] = b; out[2] = c; out[3] = q;
    }
}

// fallback scatter (unsorted path): keep seid
__global__ void k_scatter(const int* __restrict__ src, const int* __restrict__ dst,
                          int* __restrict__ cursor, int* __restrict__ seid, int* __restrict__ ssrc, int e_total) {
    int e = blockIdx.x * 256 + threadIdx.x;
    if (e < e_total) {
        int d = dst[e];
        int p = atomicAdd(&cursor[d], 1);
        seid[p] = e;
        ssrc[p] = src[e];
    }
}

// ---------------- h = x @ Wp + bp  ([N,64]@[64,128]) ----------------

__global__ __launch_bounds__(256) void k_proj(const float* __restrict__ x, const float* __restrict__ Wp,
                                              const float* __restrict__ bp, float* __restrict__ h, int n) {
    __shared__ float shx[32 * 64];
    __shared__ float shw[64 * 128];
    int t = threadIdx.x;
    int row0 = blockIdx.x * 32;
    int nrows = min(32, n - row0);

    for (int i = t; i < 64 * 128 / 4; i += 256)
        ((float4*)shw)[i] = ((const float4*)Wp)[i];
    for (int i = t; i < 32 * 64 / 4; i += 256) {
        int r = i >> 4;
        float4 v = make_float4(0.f, 0.f, 0.f, 0.f);
        if (r < nrows) v = ((const float4*)x)[row0 * 16 + i];
        ((float4*)shx)[i] = v;
    }
    __syncthreads();

    int tr = (t >> 5) * 4;
    int tc = (t & 31) * 4;
    float acc[4][4];
    float4 b4 = *(const float4*)&bp[tc];
#pragma unroll
    for (int j = 0; j < 4; j++) { acc[j][0] = b4.x; acc[j][1] = b4.y; acc[j][2] = b4.z; acc[j][3] = b4.w; }

    for (int k = 0; k < 64; k++) {
        float4 w = *(float4*)&shw[k * 128 + tc];
#pragma unroll
        for (int j = 0; j < 4; j++) {
            float a = shx[(tr + j) * 64 + k];
            acc[j][0] = fmaf(a, w.x, acc[j][0]);
            acc[j][1] = fmaf(a, w.y, acc[j][1]);
            acc[j][2] = fmaf(a, w.z, acc[j][2]);
            acc[j][3] = fmaf(a, w.w, acc[j][3]);
        }
    }
#pragma unroll
    for (int j = 0; j < 4; j++) {
        int r = row0 + tr + j;
        if (r < n) {
            float4 o = make_float4(acc[j][0], acc[j][1], acc[j][2], acc[j][3]);
            *(float4*)&h[r * 128 + tc] = o;
        }
    }
}

// ---------------- fused LayerNorm + dual GEMM: 64-row tiles, 512 threads ----------------
// Halves per-row weight restaging vs the 32-row version (782 blocks x 128KB
// instead of 1563 x 128KB). LDS 64KB -> 2 blocks/CU.

__global__ __launch_bounds__(512) void k_ln_gemm(const float* __restrict__ h,
                                                 const float* __restrict__ lng, const float* __restrict__ lnb,
                                                 const float* __restrict__ Wl, const float* __restrict__ bl,
                                                 const float* __restrict__ Wr, const float* __restrict__ br,
                                                 float* __restrict__ xl, float* __restrict__ xr, int n) {
    __shared__ float shn[64 * 128];   // 32 KB
    __shared__ float shwl[32 * 128];  // 16 KB
    __shared__ float shwr[32 * 128];  // 16 KB
    __shared__ float smu[64], srs[64];
    int t = threadIdx.x;
    int row0 = blockIdx.x * 64;
    int nrows = min(64, n - row0);

    for (int i = t; i < 2048; i += 512) {
        int r = i >> 5;
        float4 v = make_float4(0.f, 0.f, 0.f, 0.f);
        if (r < nrows) v = ((const float4*)h)[row0 * 32 + i];
        ((float4*)shn)[i] = v;
    }
    __syncthreads();

    {
        int r = t >> 3, sl = t & 7;
        float s = 0.f, ss = 0.f;
        for (int c = sl; c < 128; c += 8) {
            float v = shn[r * 128 + c];
            s += v; ss += v * v;
        }
#pragma unroll
        for (int o = 1; o < 8; o <<= 1) { s += __shfl_xor(s, o, 64); ss += __shfl_xor(ss, o, 64); }
        if (sl == 0) {
            float mu = s * (1.f / 128.f);
            float var = ss * (1.f / 128.f) - mu * mu;
            smu[r] = mu;
            srs[r] = rsqrtf(var + 1e-5f);
        }
    }
    __syncthreads();
    for (int i = t; i < 8192; i += 512) {
        int r = i >> 7, c = i & 127;
        shn[i] = (shn[i] - smu[r]) * srs[r] * lng[c] + lnb[c];
    }

    int tr = (t >> 5) * 4;   // 16 row-groups x 4 = 64 rows
    int tc = (t & 31) * 4;   // 32 col-groups x 4 = 128 cols
    float accl[4][4], accr[4][4];
    {
        float4 bl4 = *(const float4*)&bl[tc];
        float4 br4 = *(const float4*)&br[tc];
#pragma unroll
        for (int j = 0; j < 4; j++) {
            accl[j][0] = bl4.x; accl[j][1] = bl4.y; accl[j][2] = bl4.z; accl[j][3] = bl4.w;
            accr[j][0] = br4.x; accr[j][1] = br4.y; accr[j][2] = br4.z; accr[j][3] = br4.w;
        }
    }

    for (int kb = 0; kb < 4; kb++) {
        __syncthreads();
        for (int i = t; i < 1024; i += 512) {
            ((float4*)shwl)[i] = ((const float4*)Wl)[kb * 1024 + i];
            ((float4*)shwr)[i] = ((const float4*)Wr)[kb * 1024 + i];
        }
        __syncthreads();
#pragma unroll 8
        for (int kk = 0; kk < 32; kk++) {
            int k = kb * 32 + kk;
            float4 wl4 = *(float4*)&shwl[kk * 128 + tc];
            float4 wr4 = *(float4*)&shwr[kk * 128 + tc];
#pragma unroll
            for (int j = 0; j < 4; j++) {
                float a = shn[(tr + j) * 128 + k];
                accl[j][0] = fmaf(a, wl4.x, accl[j][0]);
                accl[j][1] = fmaf(a, wl4.y, accl[j][1]);
                accl[j][2] = fmaf(a, wl4.z, accl[j][2]);
                accl[j][3] = fmaf(a, wl4.w, accl[j][3]);
                accr[j][0] = fmaf(a, wr4.x, accr[j][0]);
                accr[j][1] = fmaf(a, wr4.y, accr[j][1]);
                accr[j][2] = fmaf(a, wr4.z, accr[j][2]);
                accr[j][3] = fmaf(a, wr4.w, accr[j][3]);
            }
        }
    }
#pragma unroll
    for (int j = 0; j < 4; j++) {
        int r = row0 + tr + j;
        if (r < n) {
            float4 ol = make_float4(accl[j][0], accl[j][1], accl[j][2], accl[j][3]);
            float4 orr = make_float4(accr[j][0], accr[j][1], accr[j][2], accr[j][3]);
            *(float4*)&xl[r * 128 + tc] = ol;
            *(float4*)&xr[r * 128 + tc] = orr;
        }
    }
}

// ---------------- GAT aggregate v9: G=8 pipeline at full residency ----------------
// v8's G=8 code compiled to 48 VGPR -> fits the 64-VGPR budget of 8 waves/EU.
// lb(256,8) + 2048 blocks = 32 waves/CU capacity. Spill tell: WRITE_SIZE.

#define AGG_BLOCKS 2048

template <bool SORTED, int G>
__device__ __forceinline__ void grpN(const float* __restrict__ xl_lane, const float* __restrict__ eattr,
                                     const int* __restrict__ seid, const int* __restrict__ ssrc,
                                     int j, v2f xr2, const v2f* we, v2f av,
                                     float& den, v2f& A) {
    v2f lx[G];
    const float* ep[G];
#pragma unroll
    for (int g = 0; g < G; g++) {
        int sn = rfl(ssrc[j + g]);
        lx[g] = *(const v2f*)(xl_lane + sn * 128);
        int r = SORTED ? (j + g) : rfl(seid[j + g]);
        ep[g] = &eattr[(size_t)r * 16];
    }
    v2f v[G];
#pragma unroll
    for (int g = 0; g < G; g++) v[g] = lx[g] + xr2;
#pragma unroll
    for (int k = 0; k < 16; k++) {
#pragma unroll
        for (int g = 0; g < G; g++) v[g] = pkfma(pksplat(ep[g][k]), we[k], v[g]);
    }
    float p[G];
#pragma unroll
    for (int g = 0; g < G; g++) {
        v2f t = pklrelu(v[g]) * av;
        p[g] = t.x + t.y;
    }
#pragma unroll
    for (int o = 1; o <= 16; o <<= 1) {
#pragma unroll
        for (int g = 0; g < G; g++) p[g] += __shfl_xor(p[g], o, 64);
    }
#pragma unroll
    for (int g = 0; g < G; g++) {
        float wv = __expf(p[g]);
        den += wv;
        A = pkfma(pksplat(wv), lx[g], A);
    }
}

template <bool SORTED>
__global__ __launch_bounds__(256, 8) void k_gat_agg9(const float* __restrict__ xl, const float* __restrict__ xr,
                                                     const float* __restrict__ eattr,
                                                     const int* __restrict__ offs,
                                                     const int* __restrict__ seid, const int* __restrict__ ssrc,
                                                     const float* __restrict__ We, const float* __restrict__ att,
                                                     const float* __restrict__ bout, float* __restrict__ h, int n) {
    int wid = threadIdx.x >> 6;
    int lane = threadIdx.x & 63;
    int gwave = blockIdx.x * 4 + wid;
    const int nwaves = AGG_BLOCKS * 4;

    int chb = (lane >> 5) * 64 + (lane & 31) * 2;
    const float* xl_lane = xl + chb;

    v2f we[16];
#pragma unroll
    for (int k = 0; k < 16; k++) we[k] = *(const v2f*)&We[k * 128 + chb];
    v2f av = *(const v2f*)&att[chb];
    v2f bo = *(const v2f*)&bout[chb];

    for (int node = gwave; node < n; node += nwaves) {
        v2f xr2 = *(const v2f*)&xr[node * 128 + chb];
        int s = rfl(offs[node]);
        int e = rfl(offs[node + 1]);
        float den = 0.f;
        v2f A = pksplat(0.f);

        int j = s;
        for (; j + 8 <= e; j += 8)
            grpN<SORTED, 8>(xl_lane, eattr, seid, ssrc, j, xr2, we, av, den, A);
        if (j + 4 <= e) {
            grpN<SORTED, 4>(xl_lane, eattr, seid, ssrc, j, xr2, we, av, den, A);
            j += 4;
        }
        for (; j < e; j++)
            grpN<SORTED, 1>(xl_lane, eattr, seid, ssrc, j, xr2, we, av, den, A);

        float inv = (e > s) ? (1.f / den) : 0.f;
        v2f hg = pkfma(A, pksplat(inv), bo);
        hg = __builtin_elementwise_max(hg, pksplat(0.f));
        v2f* hp = (v2f*)&h[node * 128 + chb];
        *hp = *hp + hg;
    }
}

// ---------------- classifier + embedding write ----------------

__global__ __launch_bounds__(256) void k_cls(const float* __restrict__ h, const float* __restrict__ Wc,
                                             const float* __restrict__ bc,
                                             float* __restrict__ out_cls, float* __restrict__ out_emb, int n) {
    int wid = threadIdx.x >> 6;
    int lane = threadIdx.x & 63;
    int node = blockIdx.x * 4 + wid;
    if (node >= n) return;
    float h0 = h[(size_t)node * 128 + lane];
    float h1 = h[(size_t)node * 128 + 64 + lane];
    float p[10];
#pragma unroll
    for (int k = 0; k < 10; k++) p[k] = h0 * Wc[lane * 10 + k] + h1 * Wc[(64 + lane) * 10 + k];
#pragma unroll
    for (int o = 32; o; o >>= 1) {
#pragma unroll
        for (int k = 0; k < 10; k++) p[k] += __shfl_xor(p[k], o, 64);
    }
    if (lane == 0) {
#pragma unroll
        for (int k = 0; k < 10; k++) out_cls[(size_t)node * 10 + k] = p[k] + bc[k];
    }
    out_emb[(size_t)node * 128 + lane] = h0;
    out_emb[(size_t)node * 128 + 64 + lane] = h1;
}

extern "C" void kernel_launch(void* const* d_in, const int* in_sizes, int n_in,
                              void* d_out, int out_size, void* d_ws, size_t ws_size,
                              hipStream_t stream) {
    const float* x         = (const float*)d_in[0];
    const int*   edge_idx  = (const int*)d_in[1];
    const float* edge_attr = (const float*)d_in[2];
    const float* Wp        = (const float*)d_in[3];
    const float* bp        = (const float*)d_in[4];
    const float* lng       = (const float*)d_in[5];
    const float* lnb       = (const float*)d_in[6];
    const float* Wl        = (const float*)d_in[7];
    const float* bl        = (const float*)d_in[8];
    const float* Wr        = (const float*)d_in[9];
    const float* br        = (const float*)d_in[10];
    const float* We        = (const float*)d_in[11];
    const float* att       = (const float*)d_in[12];
    const float* bout      = (const float*)d_in[13];
    const float* Wc        = (const float*)d_in[14];
    const float* bc        = (const float*)d_in[15];

    const int N = N_NODES, E = N_EDGES;

    char* w = (char*)d_ws;
    size_t used = 0;
    auto take = [&](size_t bytes) -> void* {
        void* p = (void*)(w + used);
        used += (bytes + 255) & ~(size_t)255;
        return p;
    };
    float* h      = (float*)take((size_t)N * 128 * 4);
    float* xl     = (float*)take((size_t)N * 128 * 4);
    float* xr     = (float*)take((size_t)N * 128 * 4);
    int*   indeg  = (int*)take((size_t)N * 4);
    int*   offs   = (int*)take((size_t)(N + 1) * 4);
    int*   cursor = (int*)take((size_t)N * 4);
    int*   bsum   = (int*)take(64 * 4);
    int*   seid   = (int*)take((size_t)E * 4);
    int*   ssrc   = (int*)take((size_t)E * 4);
    float* sea    = (float*)take((size_t)E * 16 * 4);
    bool sorted_ok = (used <= ws_size);

    const int* srcArr = edge_idx;
    const int* dstArr = edge_idx + E;

    (void)hipMemsetAsync(indeg, 0, (size_t)N * 4, stream);
    k_count<<<(E + 255) / 256, 256, 0, stream>>>(dstArr, indeg, E);
    int NB = (N + 1023) / 1024;
    k_scan_block<<<NB, 1024, 0, stream>>>(indeg, offs, bsum, N);
    k_scan_small<<<1, 64, 0, stream>>>(bsum, NB);
    k_scan_add<<<NB, 1024, 0, stream>>>(offs, bsum, cursor, N, E);
    if (sorted_ok)
        k_scatter_fused<<<(E + 255) / 256, 256, 0, stream>>>(srcArr, dstArr, edge_attr, cursor, ssrc, sea, E);
    else
        k_scatter<<<(E + 255) / 256, 256, 0, stream>>>(srcArr, dstArr, cursor, seid, ssrc, E);

    k_proj<<<(N + 31) / 32, 256, 0, stream>>>(x, Wp, bp, h, N);

    for (int i = 0; i < 2; i++) {
        k_ln_gemm<<<(N + 63) / 64, 512, 0, stream>>>(
            h, lng + i * 128, lnb + i * 128,
            Wl + (size_t)i * 128 * 128, bl + i * 128,
            Wr + (size_t)i * 128 * 128, br + i * 128,
            xl, xr, N);
        if (sorted_ok)
            k_gat_agg9<true><<<AGG_BLOCKS, 256, 0, stream>>>(
                xl, xr, sea, offs, seid, ssrc,
                We + (size_t)i * 16 * 128, att + i * 128, bout + i * 128, h, N);
        else
            k_gat_agg9<false><<<AGG_BLOCKS, 256, 0, stream>>>(
                xl, xr, edge_attr, offs, seid, ssrc,
                We + (size_t)i * 16 * 128, att + i * 128, bout + i * 128, h, N);
    }

    k_cls<<<(N + 3) / 4, 256, 0, stream>>>(h, Wc, bc, (float*)d_out, (float*)d_out + (size_t)N * KCLS, N);
}

// Round 11
// 461.567 us; speedup vs baseline: 1.7006x; 1.7006x over previous
//
#include <hip/hip_runtime.h>
#include <math.h>

#define N_NODES 50000
#define N_EDGES 800000
#define FDIM 128
#define KCLS 10

typedef float v2f __attribute__((ext_vector_type(2)));

__device__ __forceinline__ v2f pksplat(float a) { v2f r; r.x = a; r.y = a; return r; }
__device__ __forceinline__ v2f pkfma(v2f a, v2f b, v2f c) { return __builtin_elementwise_fma(a, b, c); }
__device__ __forceinline__ v2f pklrelu(v2f v) {
    v2f z = pksplat(0.f);
    v2f mx = __builtin_elementwise_max(v, z);
    v2f mn = __builtin_elementwise_min(v, z);
    return pkfma(pksplat(0.2f), mn, mx);
}
__device__ __forceinline__ int rfl(int v) { return __builtin_amdgcn_readfirstlane(v); }

// ---------------- CSR build ----------------

__global__ void k_count(const int* __restrict__ dst, int* __restrict__ indeg, int e_total) {
    int e = blockIdx.x * 256 + threadIdx.x;
    if (e < e_total) atomicAdd(&indeg[dst[e]], 1);
}

__global__ __launch_bounds__(1024) void k_scan_block(const int* __restrict__ in, int* __restrict__ excl,
                                                     int* __restrict__ bsum, int n) {
    __shared__ int sh[1024];
    int t = threadIdx.x;
    int g = blockIdx.x * 1024 + t;
    int v = (g < n) ? in[g] : 0;
    sh[t] = v;
    __syncthreads();
    for (int d = 1; d < 1024; d <<= 1) {
        int x = (t >= d) ? sh[t - d] : 0;
        __syncthreads();
        sh[t] += x;
        __syncthreads();
    }
    if (g < n) excl[g] = sh[t] - v;
    if (t == 1023) bsum[blockIdx.x] = sh[t];
}

__global__ void k_scan_small(int* bsum, int nb) {
    if (threadIdx.x == 0 && blockIdx.x == 0) {
        int run = 0;
        for (int i = 0; i < nb; i++) { int v = bsum[i]; bsum[i] = run; run += v; }
    }
}

__global__ __launch_bounds__(1024) void k_scan_add(int* __restrict__ offs, const int* __restrict__ bsum,
                                                   int* __restrict__ cursor, int n, int e_total) {
    int g = blockIdx.x * 1024 + threadIdx.x;
    if (g < n) {
        int v = offs[g] + bsum[blockIdx.x];
        offs[g] = v;
        cursor[g] = v;
    }
    if (g == 0) offs[n] = e_total;
}

// scatter edges into CSR order; fused: also permute edge_attr rows into sea
__global__ void k_scatter_fused(const int* __restrict__ src, const int* __restrict__ dst,
                                const float* __restrict__ edge_attr,
                                int* __restrict__ cursor, int* __restrict__ ssrc,
                                float* __restrict__ sea, int e_total) {
    int e = blockIdx.x * 256 + threadIdx.x;
    if (e < e_total) {
        int d = dst[e];
        int p = atomicAdd(&cursor[d], 1);
        ssrc[p] = src[e];
        const float4* ea = (const float4*)&edge_attr[(size_t)e * 16];
        float4* out = (float4*)&sea[(size_t)p * 16];
        float4 a = ea[0], b = ea[1], c = ea[2], q = ea[3];
        out[0] = a; out[1] = b; out[2] = c; out[3] = q;
    }
}

// fallback scatter (unsorted path): keep seid
__global__ void k_scatter(const int* __restrict__ src, const int* __restrict__ dst,
                          int* __restrict__ cursor, int* __restrict__ seid, int* __restrict__ ssrc, int e_total) {
    int e = blockIdx.x * 256 + threadIdx.x;
    if (e < e_total) {
        int d = dst[e];
        int p = atomicAdd(&cursor[d], 1);
        seid[p] = e;
        ssrc[p] = src[e];
    }
}

// ---------------- h = x @ Wp + bp  ([N,64]@[64,128]) ----------------

__global__ __launch_bounds__(256) void k_proj(const float* __restrict__ x, const float* __restrict__ Wp,
                                              const float* __restrict__ bp, float* __restrict__ h, int n) {
    __shared__ float shx[32 * 64];
    __shared__ float shw[64 * 128];
    int t = threadIdx.x;
    int row0 = blockIdx.x * 32;
    int nrows = min(32, n - row0);

    for (int i = t; i < 64 * 128 / 4; i += 256)
        ((float4*)shw)[i] = ((const float4*)Wp)[i];
    for (int i = t; i < 32 * 64 / 4; i += 256) {
        int r = i >> 4;
        float4 v = make_float4(0.f, 0.f, 0.f, 0.f);
        if (r < nrows) v = ((const float4*)x)[row0 * 16 + i];
        ((float4*)shx)[i] = v;
    }
    __syncthreads();

    int tr = (t >> 5) * 4;
    int tc = (t & 31) * 4;
    float acc[4][4];
    float4 b4 = *(const float4*)&bp[tc];
#pragma unroll
    for (int j = 0; j < 4; j++) { acc[j][0] = b4.x; acc[j][1] = b4.y; acc[j][2] = b4.z; acc[j][3] = b4.w; }

    for (int k = 0; k < 64; k++) {
        float4 w = *(float4*)&shw[k * 128 + tc];
#pragma unroll
        for (int j = 0; j < 4; j++) {
            float a = shx[(tr + j) * 64 + k];
            acc[j][0] = fmaf(a, w.x, acc[j][0]);
            acc[j][1] = fmaf(a, w.y, acc[j][1]);
            acc[j][2] = fmaf(a, w.z, acc[j][2]);
            acc[j][3] = fmaf(a, w.w, acc[j][3]);
        }
    }
#pragma unroll
    for (int j = 0; j < 4; j++) {
        int r = row0 + tr + j;
        if (r < n) {
            float4 o = make_float4(acc[j][0], acc[j][1], acc[j][2], acc[j][3]);
            *(float4*)&h[r * 128 + tc] = o;
        }
    }
}

// ---------------- fused LayerNorm + dual GEMM: 64-row tiles, 512 threads ----------------

__global__ __launch_bounds__(512) void k_ln_gemm(const float* __restrict__ h,
                                                 const float* __restrict__ lng, const float* __restrict__ lnb,
                                                 const float* __restrict__ Wl, const float* __restrict__ bl,
                                                 const float* __restrict__ Wr, const float* __restrict__ br,
                                                 float* __restrict__ xl, float* __restrict__ xr, int n) {
    __shared__ float shn[64 * 128];   // 32 KB
    __shared__ float shwl[32 * 128];  // 16 KB
    __shared__ float shwr[32 * 128];  // 16 KB
    __shared__ float smu[64], srs[64];
    int t = threadIdx.x;
    int row0 = blockIdx.x * 64;
    int nrows = min(64, n - row0);

    for (int i = t; i < 2048; i += 512) {
        int r = i >> 5;
        float4 v = make_float4(0.f, 0.f, 0.f, 0.f);
        if (r < nrows) v = ((const float4*)h)[row0 * 32 + i];
        ((float4*)shn)[i] = v;
    }
    __syncthreads();

    {
        int r = t >> 3, sl = t & 7;
        float s = 0.f, ss = 0.f;
        for (int c = sl; c < 128; c += 8) {
            float v = shn[r * 128 + c];
            s += v; ss += v * v;
        }
#pragma unroll
        for (int o = 1; o < 8; o <<= 1) { s += __shfl_xor(s, o, 64); ss += __shfl_xor(ss, o, 64); }
        if (sl == 0) {
            float mu = s * (1.f / 128.f);
            float var = ss * (1.f / 128.f) - mu * mu;
            smu[r] = mu;
            srs[r] = rsqrtf(var + 1e-5f);
        }
    }
    __syncthreads();
    for (int i = t; i < 8192; i += 512) {
        int r = i >> 7, c = i & 127;
        shn[i] = (shn[i] - smu[r]) * srs[r] * lng[c] + lnb[c];
    }

    int tr = (t >> 5) * 4;
    int tc = (t & 31) * 4;
    float accl[4][4], accr[4][4];
    {
        float4 bl4 = *(const float4*)&bl[tc];
        float4 br4 = *(const float4*)&br[tc];
#pragma unroll
        for (int j = 0; j < 4; j++) {
            accl[j][0] = bl4.x; accl[j][1] = bl4.y; accl[j][2] = bl4.z; accl[j][3] = bl4.w;
            accr[j][0] = br4.x; accr[j][1] = br4.y; accr[j][2] = br4.z; accr[j][3] = br4.w;
        }
    }

    for (int kb = 0; kb < 4; kb++) {
        __syncthreads();
        for (int i = t; i < 1024; i += 512) {
            ((float4*)shwl)[i] = ((const float4*)Wl)[kb * 1024 + i];
            ((float4*)shwr)[i] = ((const float4*)Wr)[kb * 1024 + i];
        }
        __syncthreads();
#pragma unroll 8
        for (int kk = 0; kk < 32; kk++) {
            int k = kb * 32 + kk;
            float4 wl4 = *(float4*)&shwl[kk * 128 + tc];
            float4 wr4 = *(float4*)&shwr[kk * 128 + tc];
#pragma unroll
            for (int j = 0; j < 4; j++) {
                float a = shn[(tr + j) * 128 + k];
                accl[j][0] = fmaf(a, wl4.x, accl[j][0]);
                accl[j][1] = fmaf(a, wl4.y, accl[j][1]);
                accl[j][2] = fmaf(a, wl4.z, accl[j][2]);
                accl[j][3] = fmaf(a, wl4.w, accl[j][3]);
                accr[j][0] = fmaf(a, wr4.x, accr[j][0]);
                accr[j][1] = fmaf(a, wr4.y, accr[j][1]);
                accr[j][2] = fmaf(a, wr4.z, accr[j][2]);
                accr[j][3] = fmaf(a, wr4.w, accr[j][3]);
            }
        }
    }
#pragma unroll
    for (int j = 0; j < 4; j++) {
        int r = row0 + tr + j;
        if (r < n) {
            float4 ol = make_float4(accl[j][0], accl[j][1], accl[j][2], accl[j][3]);
            float4 orr = make_float4(accr[j][0], accr[j][1], accr[j][2], accr[j][3]);
            *(float4*)&xl[r * 128 + tc] = ol;
            *(float4*)&xr[r * 128 + tc] = orr;
        }
    }
}

// ---------------- GAT aggregate v10 = v8 exact (lb(256,5), 1280 blocks, G=8) ----------------
// + exp2-domain logits: att pre-scaled by log2(e) on load, so exp(p) = exp2(p')
// with one v_exp and no multiply. 64-VGPR budgets (waves/EU >= 6) spill this
// kernel (R7/R8/R10 evidence) -- do not lower the budget below 102.

#define AGG_BLOCKS 1280

template <bool SORTED, int G>
__device__ __forceinline__ void grpN(const float* __restrict__ xl_lane, const float* __restrict__ eattr,
                                     const int* __restrict__ seid, const int* __restrict__ ssrc,
                                     int j, v2f xr2, const v2f* we, v2f av,
                                     float& den, v2f& A) {
    v2f lx[G];
    const float* ep[G];
#pragma unroll
    for (int g = 0; g < G; g++) {
        int sn = rfl(ssrc[j + g]);
        lx[g] = *(const v2f*)(xl_lane + sn * 128);
        int r = SORTED ? (j + g) : rfl(seid[j + g]);
        ep[g] = &eattr[(size_t)r * 16];
    }
    v2f v[G];
#pragma unroll
    for (int g = 0; g < G; g++) v[g] = lx[g] + xr2;
#pragma unroll
    for (int k = 0; k < 16; k++) {
#pragma unroll
        for (int g = 0; g < G; g++) v[g] = pkfma(pksplat(ep[g][k]), we[k], v[g]);
    }
    float p[G];
#pragma unroll
    for (int g = 0; g < G; g++) {
        v2f t = pklrelu(v[g]) * av;   // av already carries log2(e)
        p[g] = t.x + t.y;
    }
#pragma unroll
    for (int o = 1; o <= 16; o <<= 1) {
#pragma unroll
        for (int g = 0; g < G; g++) p[g] += __shfl_xor(p[g], o, 64);
    }
#pragma unroll
    for (int g = 0; g < G; g++) {
        float wv = exp2f(p[g]);       // exp(logit) in exp2 domain
        den += wv;
        A = pkfma(pksplat(wv), lx[g], A);
    }
}

template <bool SORTED>
__global__ __launch_bounds__(256, 5) void k_gat_agg10(const float* __restrict__ xl, const float* __restrict__ xr,
                                                      const float* __restrict__ eattr,
                                                      const int* __restrict__ offs,
                                                      const int* __restrict__ seid, const int* __restrict__ ssrc,
                                                      const float* __restrict__ We, const float* __restrict__ att,
                                                      const float* __restrict__ bout, float* __restrict__ h, int n) {
    int wid = threadIdx.x >> 6;
    int lane = threadIdx.x & 63;
    int gwave = blockIdx.x * 4 + wid;
    const int nwaves = AGG_BLOCKS * 4;

    int chb = (lane >> 5) * 64 + (lane & 31) * 2;
    const float* xl_lane = xl + chb;

    v2f we[16];
#pragma unroll
    for (int k = 0; k < 16; k++) we[k] = *(const v2f*)&We[k * 128 + chb];
    v2f av = *(const v2f*)&att[chb] * pksplat(1.4426950408889634f);  // fold log2(e)
    v2f bo = *(const v2f*)&bout[chb];

    for (int node = gwave; node < n; node += nwaves) {
        v2f xr2 = *(const v2f*)&xr[node * 128 + chb];
        int s = rfl(offs[node]);
        int e = rfl(offs[node + 1]);
        float den = 0.f;
        v2f A = pksplat(0.f);

        int j = s;
        for (; j + 8 <= e; j += 8)
            grpN<SORTED, 8>(xl_lane, eattr, seid, ssrc, j, xr2, we, av, den, A);
        if (j + 4 <= e) {
            grpN<SORTED, 4>(xl_lane, eattr, seid, ssrc, j, xr2, we, av, den, A);
            j += 4;
        }
        for (; j < e; j++)
            grpN<SORTED, 1>(xl_lane, eattr, seid, ssrc, j, xr2, we, av, den, A);

        float inv = (e > s) ? (1.f / den) : 0.f;
        v2f hg = pkfma(A, pksplat(inv), bo);
        hg = __builtin_elementwise_max(hg, pksplat(0.f));
        v2f* hp = (v2f*)&h[node * 128 + chb];
        *hp = *hp + hg;
    }
}

// ---------------- classifier + embedding write ----------------

__global__ __launch_bounds__(256) void k_cls(const float* __restrict__ h, const float* __restrict__ Wc,
                                             const float* __restrict__ bc,
                                             float* __restrict__ out_cls, float* __restrict__ out_emb, int n) {
    int wid = threadIdx.x >> 6;
    int lane = threadIdx.x & 63;
    int node = blockIdx.x * 4 + wid;
    if (node >= n) return;
    float h0 = h[(size_t)node * 128 + lane];
    float h1 = h[(size_t)node * 128 + 64 + lane];
    float p[10];
#pragma unroll
    for (int k = 0; k < 10; k++) p[k] = h0 * Wc[lane * 10 + k] + h1 * Wc[(64 + lane) * 10 + k];
#pragma unroll
    for (int o = 32; o; o >>= 1) {
#pragma unroll
        for (int k = 0; k < 10; k++) p[k] += __shfl_xor(p[k], o, 64);
    }
    if (lane == 0) {
#pragma unroll
        for (int k = 0; k < 10; k++) out_cls[(size_t)node * 10 + k] = p[k] + bc[k];
    }
    out_emb[(size_t)node * 128 + lane] = h0;
    out_emb[(size_t)node * 128 + 64 + lane] = h1;
}

extern "C" void kernel_launch(void* const* d_in, const int* in_sizes, int n_in,
                              void* d_out, int out_size, void* d_ws, size_t ws_size,
                              hipStream_t stream) {
    const float* x         = (const float*)d_in[0];
    const int*   edge_idx  = (const int*)d_in[1];
    const float* edge_attr = (const float*)d_in[2];
    const float* Wp        = (const float*)d_in[3];
    const float* bp        = (const float*)d_in[4];
    const float* lng       = (const float*)d_in[5];
    const float* lnb       = (const float*)d_in[6];
    const float* Wl        = (const float*)d_in[7];
    const float* bl        = (const float*)d_in[8];
    const float* Wr        = (const float*)d_in[9];
    const float* br        = (const float*)d_in[10];
    const float* We        = (const float*)d_in[11];
    const float* att       = (const float*)d_in[12];
    const float* bout      = (const float*)d_in[13];
    const float* Wc        = (const float*)d_in[14];
    const float* bc        = (const float*)d_in[15];

    const int N = N_NODES, E = N_EDGES;

    char* w = (char*)d_ws;
    size_t used = 0;
    auto take = [&](size_t bytes) -> void* {
        void* p = (void*)(w + used);
        used += (bytes + 255) & ~(size_t)255;
        return p;
    };
    float* h      = (float*)take((size_t)N * 128 * 4);
    float* xl     = (float*)take((size_t)N * 128 * 4);
    float* xr     = (float*)take((size_t)N * 128 * 4);
    int*   indeg  = (int*)take((size_t)N * 4);
    int*   offs   = (int*)take((size_t)(N + 1) * 4);
    int*   cursor = (int*)take((size_t)N * 4);
    int*   bsum   = (int*)take(64 * 4);
    int*   seid   = (int*)take((size_t)E * 4);
    int*   ssrc   = (int*)take((size_t)E * 4);
    float* sea    = (float*)take((size_t)E * 16 * 4);
    bool sorted_ok = (used <= ws_size);

    const int* srcArr = edge_idx;
    const int* dstArr = edge_idx + E;

    (void)hipMemsetAsync(indeg, 0, (size_t)N * 4, stream);
    k_count<<<(E + 255) / 256, 256, 0, stream>>>(dstArr, indeg, E);
    int NB = (N + 1023) / 1024;
    k_scan_block<<<NB, 1024, 0, stream>>>(indeg, offs, bsum, N);
    k_scan_small<<<1, 64, 0, stream>>>(bsum, NB);
    k_scan_add<<<NB, 1024, 0, stream>>>(offs, bsum, cursor, N, E);
    if (sorted_ok)
        k_scatter_fused<<<(E + 255) / 256, 256, 0, stream>>>(srcArr, dstArr, edge_attr, cursor, ssrc, sea, E);
    else
        k_scatter<<<(E + 255) / 256, 256, 0, stream>>>(srcArr, dstArr, cursor, seid, ssrc, E);

    k_proj<<<(N + 31) / 32, 256, 0, stream>>>(x, Wp, bp, h, N);

    for (int i = 0; i < 2; i++) {
        k_ln_gemm<<<(N + 63) / 64, 512, 0, stream>>>(
            h, lng + i * 128, lnb + i * 128,
            Wl + (size_t)i * 128 * 128, bl + i * 128,
            Wr + (size_t)i * 128 * 128, br + i * 128,
            xl, xr, N);
        if (sorted_ok)
            k_gat_agg10<true><<<AGG_BLOCKS, 256, 0, stream>>>(
                xl, xr, sea, offs, seid, ssrc,
                We + (size_t)i * 16 * 128, att + i * 128, bout + i * 128, h, N);
        else
            k_gat_agg10<false><<<AGG_BLOCKS, 256, 0, stream>>>(
                xl, xr, edge_attr, offs, seid, ssrc,
                We + (size_t)i * 16 * 128, att + i * 128, bout + i * 128, h, N);
    }

    k_cls<<<(N + 3) / 4, 256, 0, stream>>>(h, Wc, bc, (float*)d_out, (float*)d_out + (size_t)N * KCLS, N);
}

// Round 12
// 452.073 us; speedup vs baseline: 1.7364x; 1.0210x over previous
//
#include <hip/hip_runtime.h>
#include <math.h>

#define N_NODES 50000
#define N_EDGES 800000
#define FDIM 128
#define KCLS 10

typedef float v2f __attribute__((ext_vector_type(2)));

__device__ __forceinline__ v2f pksplat(float a) { v2f r; r.x = a; r.y = a; return r; }
__device__ __forceinline__ v2f pkfma(v2f a, v2f b, v2f c) { return __builtin_elementwise_fma(a, b, c); }
__device__ __forceinline__ v2f pklrelu(v2f v) {
    v2f z = pksplat(0.f);
    v2f mx = __builtin_elementwise_max(v, z);
    v2f mn = __builtin_elementwise_min(v, z);
    return pkfma(pksplat(0.2f), mn, mx);
}
__device__ __forceinline__ int rfl(int v) { return __builtin_amdgcn_readfirstlane(v); }

// ---------------- CSR build ----------------

__global__ void k_count(const int* __restrict__ dst, int* __restrict__ indeg, int e_total) {
    int e = blockIdx.x * 256 + threadIdx.x;
    if (e < e_total) atomicAdd(&indeg[dst[e]], 1);
}

__global__ __launch_bounds__(1024) void k_scan_block(const int* __restrict__ in, int* __restrict__ excl,
                                                     int* __restrict__ bsum, int n) {
    __shared__ int sh[1024];
    int t = threadIdx.x;
    int g = blockIdx.x * 1024 + t;
    int v = (g < n) ? in[g] : 0;
    sh[t] = v;
    __syncthreads();
    for (int d = 1; d < 1024; d <<= 1) {
        int x = (t >= d) ? sh[t - d] : 0;
        __syncthreads();
        sh[t] += x;
        __syncthreads();
    }
    if (g < n) excl[g] = sh[t] - v;
    if (t == 1023) bsum[blockIdx.x] = sh[t];
}

__global__ void k_scan_small(int* bsum, int nb) {
    if (threadIdx.x == 0 && blockIdx.x == 0) {
        int run = 0;
        for (int i = 0; i < nb; i++) { int v = bsum[i]; bsum[i] = run; run += v; }
    }
}

__global__ __launch_bounds__(1024) void k_scan_add(int* __restrict__ offs, const int* __restrict__ bsum,
                                                   int* __restrict__ cursor, int n, int e_total) {
    int g = blockIdx.x * 1024 + threadIdx.x;
    if (g < n) {
        int v = offs[g] + bsum[blockIdx.x];
        offs[g] = v;
        cursor[g] = v;
    }
    if (g == 0) offs[n] = e_total;
}

// scatter edges into CSR order; fused: also permute edge_attr rows into sea
__global__ void k_scatter_fused(const int* __restrict__ src, const int* __restrict__ dst,
                                const float* __restrict__ edge_attr,
                                int* __restrict__ cursor, int* __restrict__ ssrc,
                                float* __restrict__ sea, int e_total) {
    int e = blockIdx.x * 256 + threadIdx.x;
    if (e < e_total) {
        int d = dst[e];
        int p = atomicAdd(&cursor[d], 1);
        ssrc[p] = src[e];
        const float4* ea = (const float4*)&edge_attr[(size_t)e * 16];
        float4* out = (float4*)&sea[(size_t)p * 16];
        float4 a = ea[0], b = ea[1], c = ea[2], q = ea[3];
        out[0] = a; out[1] = b; out[2] = c; out[3] = q;
    }
}

// fallback scatter (unsorted path): keep seid
__global__ void k_scatter(const int* __restrict__ src, const int* __restrict__ dst,
                          int* __restrict__ cursor, int* __restrict__ seid, int* __restrict__ ssrc, int e_total) {
    int e = blockIdx.x * 256 + threadIdx.x;
    if (e < e_total) {
        int d = dst[e];
        int p = atomicAdd(&cursor[d], 1);
        seid[p] = e;
        ssrc[p] = src[e];
    }
}

// ---------------- layer-0 fused: h = x@Wp+bp; LN(h); xl/xr dual GEMM ----------------
// Replaces k_proj + first k_ln_gemm: saves one kernel launch and a 25.6MB
// h re-read. LDS: u 40KB (phase1 shx+shwp, phase2 shwl+shwr) + shn 16KB.

__global__ __launch_bounds__(256) void k_ln_gemm_first(const float* __restrict__ x, const float* __restrict__ Wp,
                                                       const float* __restrict__ bp,
                                                       const float* __restrict__ lng, const float* __restrict__ lnb,
                                                       const float* __restrict__ Wl, const float* __restrict__ bl,
                                                       const float* __restrict__ Wr, const float* __restrict__ br,
                                                       float* __restrict__ h, float* __restrict__ xl,
                                                       float* __restrict__ xr, int n) {
    __shared__ float u[10240];   // 40 KB union
    __shared__ float shn[4096];  // 16 KB
    __shared__ float smu[32], srs[32];
    int t = threadIdx.x;
    int row0 = blockIdx.x * 32;
    int nrows = min(32, n - row0);
    float* shx = u;          // 2048 floats
    float* shwp = u + 2048;  // 8192 floats

    for (int i = t; i < 2048; i += 256)
        ((float4*)shwp)[i] = ((const float4*)Wp)[i];
    for (int i = t; i < 512; i += 256) {
        int r = i >> 4;
        float4 v = make_float4(0.f, 0.f, 0.f, 0.f);
        if (r < nrows) v = ((const float4*)x)[row0 * 16 + i];
        ((float4*)shx)[i] = v;
    }
    __syncthreads();

    int tr = (t >> 5) * 4;
    int tc = (t & 31) * 4;
    {
        float acc[4][4];
        float4 b4 = *(const float4*)&bp[tc];
#pragma unroll
        for (int j = 0; j < 4; j++) { acc[j][0] = b4.x; acc[j][1] = b4.y; acc[j][2] = b4.z; acc[j][3] = b4.w; }
        for (int k = 0; k < 64; k++) {
            float4 w = *(float4*)&shwp[k * 128 + tc];
#pragma unroll
            for (int j = 0; j < 4; j++) {
                float a = shx[(tr + j) * 64 + k];
                acc[j][0] = fmaf(a, w.x, acc[j][0]);
                acc[j][1] = fmaf(a, w.y, acc[j][1]);
                acc[j][2] = fmaf(a, w.z, acc[j][2]);
                acc[j][3] = fmaf(a, w.w, acc[j][3]);
            }
        }
#pragma unroll
        for (int j = 0; j < 4; j++) {
            int r = row0 + tr + j;
            float4 o = make_float4(acc[j][0], acc[j][1], acc[j][2], acc[j][3]);
            *(float4*)&shn[(tr + j) * 128 + tc] = o;
            if (r < n) *(float4*)&h[r * 128 + tc] = o;
        }
    }
    __syncthreads();

    {
        int r = t >> 3, sl = t & 7;
        float s = 0.f, ss = 0.f;
        for (int c = sl; c < 128; c += 8) {
            float v = shn[r * 128 + c];
            s += v; ss += v * v;
        }
#pragma unroll
        for (int o = 1; o < 8; o <<= 1) { s += __shfl_xor(s, o, 64); ss += __shfl_xor(ss, o, 64); }
        if (sl == 0) {
            float mu = s * (1.f / 128.f);
            float var = ss * (1.f / 128.f) - mu * mu;
            smu[r] = mu;
            srs[r] = rsqrtf(var + 1e-5f);
        }
    }
    __syncthreads();
    for (int i = t; i < 4096; i += 256) {
        int r = i >> 7, c = i & 127;
        shn[i] = (shn[i] - smu[r]) * srs[r] * lng[c] + lnb[c];
    }

    float accl[4][4], accr[4][4];
    {
        float4 bl4 = *(const float4*)&bl[tc];
        float4 br4 = *(const float4*)&br[tc];
#pragma unroll
        for (int j = 0; j < 4; j++) {
            accl[j][0] = bl4.x; accl[j][1] = bl4.y; accl[j][2] = bl4.z; accl[j][3] = bl4.w;
            accr[j][0] = br4.x; accr[j][1] = br4.y; accr[j][2] = br4.z; accr[j][3] = br4.w;
        }
    }
    float* shwl = u;         // 4096
    float* shwr = u + 4096;  // 4096

    for (int kb = 0; kb < 4; kb++) {
        __syncthreads();
        for (int i = t; i < 1024; i += 256) {
            ((float4*)shwl)[i] = ((const float4*)Wl)[kb * 1024 + i];
            ((float4*)shwr)[i] = ((const float4*)Wr)[kb * 1024 + i];
        }
        __syncthreads();
#pragma unroll 8
        for (int kk = 0; kk < 32; kk++) {
            int k = kb * 32 + kk;
            float4 wl4 = *(float4*)&shwl[kk * 128 + tc];
            float4 wr4 = *(float4*)&shwr[kk * 128 + tc];
#pragma unroll
            for (int j = 0; j < 4; j++) {
                float a = shn[(tr + j) * 128 + k];
                accl[j][0] = fmaf(a, wl4.x, accl[j][0]);
                accl[j][1] = fmaf(a, wl4.y, accl[j][1]);
                accl[j][2] = fmaf(a, wl4.z, accl[j][2]);
                accl[j][3] = fmaf(a, wl4.w, accl[j][3]);
                accr[j][0] = fmaf(a, wr4.x, accr[j][0]);
                accr[j][1] = fmaf(a, wr4.y, accr[j][1]);
                accr[j][2] = fmaf(a, wr4.z, accr[j][2]);
                accr[j][3] = fmaf(a, wr4.w, accr[j][3]);
            }
        }
    }
#pragma unroll
    for (int j = 0; j < 4; j++) {
        int r = row0 + tr + j;
        if (r < n) {
            float4 ol = make_float4(accl[j][0], accl[j][1], accl[j][2], accl[j][3]);
            float4 orr = make_float4(accr[j][0], accr[j][1], accr[j][2], accr[j][3]);
            *(float4*)&xl[r * 128 + tc] = ol;
            *(float4*)&xr[r * 128 + tc] = orr;
        }
    }
}

// ---------------- layer-1 LayerNorm + dual GEMM (R9-exact 32-row) ----------------

__global__ __launch_bounds__(256) void k_ln_gemm(const float* __restrict__ h,
                                                 const float* __restrict__ lng, const float* __restrict__ lnb,
                                                 const float* __restrict__ Wl, const float* __restrict__ bl,
                                                 const float* __restrict__ Wr, const float* __restrict__ br,
                                                 float* __restrict__ xl, float* __restrict__ xr, int n) {
    __shared__ float shn[32 * 128];
    __shared__ float shwl[32 * 128];
    __shared__ float shwr[32 * 128];
    __shared__ float smu[32], srs[32];
    int t = threadIdx.x;
    int row0 = blockIdx.x * 32;
    int nrows = min(32, n - row0);

    for (int i = t; i < 1024; i += 256) {
        int r = i >> 5;
        float4 v = make_float4(0.f, 0.f, 0.f, 0.f);
        if (r < nrows) v = ((const float4*)h)[row0 * 32 + i];
        ((float4*)shn)[i] = v;
    }
    __syncthreads();

    {
        int r = t >> 3, sl = t & 7;
        float s = 0.f, ss = 0.f;
        for (int c = sl; c < 128; c += 8) {
            float v = shn[r * 128 + c];
            s += v; ss += v * v;
        }
#pragma unroll
        for (int o = 1; o < 8; o <<= 1) { s += __shfl_xor(s, o, 64); ss += __shfl_xor(ss, o, 64); }
        if (sl == 0) {
            float mu = s * (1.f / 128.f);
            float var = ss * (1.f / 128.f) - mu * mu;
            smu[r] = mu;
            srs[r] = rsqrtf(var + 1e-5f);
        }
    }
    __syncthreads();
    for (int i = t; i < 4096; i += 256) {
        int r = i >> 7, c = i & 127;
        shn[i] = (shn[i] - smu[r]) * srs[r] * lng[c] + lnb[c];
    }

    int tr = (t >> 5) * 4;
    int tc = (t & 31) * 4;
    float accl[4][4], accr[4][4];
    {
        float4 bl4 = *(const float4*)&bl[tc];
        float4 br4 = *(const float4*)&br[tc];
#pragma unroll
        for (int j = 0; j < 4; j++) {
            accl[j][0] = bl4.x; accl[j][1] = bl4.y; accl[j][2] = bl4.z; accl[j][3] = bl4.w;
            accr[j][0] = br4.x; accr[j][1] = br4.y; accr[j][2] = br4.z; accr[j][3] = br4.w;
        }
    }

    for (int kb = 0; kb < 4; kb++) {
        __syncthreads();
        for (int i = t; i < 1024; i += 256) {
            ((float4*)shwl)[i] = ((const float4*)Wl)[kb * 1024 + i];
            ((float4*)shwr)[i] = ((const float4*)Wr)[kb * 1024 + i];
        }
        __syncthreads();
#pragma unroll 8
        for (int kk = 0; kk < 32; kk++) {
            int k = kb * 32 + kk;
            float4 wl4 = *(float4*)&shwl[kk * 128 + tc];
            float4 wr4 = *(float4*)&shwr[kk * 128 + tc];
#pragma unroll
            for (int j = 0; j < 4; j++) {
                float a = shn[(tr + j) * 128 + k];
                accl[j][0] = fmaf(a, wl4.x, accl[j][0]);
                accl[j][1] = fmaf(a, wl4.y, accl[j][1]);
                accl[j][2] = fmaf(a, wl4.z, accl[j][2]);
                accl[j][3] = fmaf(a, wl4.w, accl[j][3]);
                accr[j][0] = fmaf(a, wr4.x, accr[j][0]);
                accr[j][1] = fmaf(a, wr4.y, accr[j][1]);
                accr[j][2] = fmaf(a, wr4.z, accr[j][2]);
                accr[j][3] = fmaf(a, wr4.w, accr[j][3]);
            }
        }
    }
#pragma unroll
    for (int j = 0; j < 4; j++) {
        int r = row0 + tr + j;
        if (r < n) {
            float4 ol = make_float4(accl[j][0], accl[j][1], accl[j][2], accl[j][3]);
            float4 orr = make_float4(accr[j][0], accr[j][1], accr[j][2], accr[j][3]);
            *(float4*)&xl[r * 128 + tc] = ol;
            *(float4*)&xr[r * 128 + tc] = orr;
        }
    }
}

// ---------------- GAT aggregate (R9-exact: lb(256,5), 1280 blocks, G=8, __expf) ----------------
// hin/hout split: layer 0 reads+writes h; layer 1 reads h, writes out_emb
// (out_emb == final h). 64-VGPR budgets (>=6 waves/EU) spill this kernel
// (R7/R8/R10 evidence) -- keep budget at 102.

#define AGG_BLOCKS 1280

template <bool SORTED, int G>
__device__ __forceinline__ void grpN(const float* __restrict__ xl_lane, const float* __restrict__ eattr,
                                     const int* __restrict__ seid, const int* __restrict__ ssrc,
                                     int j, v2f xr2, const v2f* we, v2f av,
                                     float& den, v2f& A) {
    v2f lx[G];
    const float* ep[G];
#pragma unroll
    for (int g = 0; g < G; g++) {
        int sn = rfl(ssrc[j + g]);
        lx[g] = *(const v2f*)(xl_lane + sn * 128);
        int r = SORTED ? (j + g) : rfl(seid[j + g]);
        ep[g] = &eattr[(size_t)r * 16];
    }
    v2f v[G];
#pragma unroll
    for (int g = 0; g < G; g++) v[g] = lx[g] + xr2;
#pragma unroll
    for (int k = 0; k < 16; k++) {
#pragma unroll
        for (int g = 0; g < G; g++) v[g] = pkfma(pksplat(ep[g][k]), we[k], v[g]);
    }
    float p[G];
#pragma unroll
    for (int g = 0; g < G; g++) {
        v2f t = pklrelu(v[g]) * av;
        p[g] = t.x + t.y;
    }
#pragma unroll
    for (int o = 1; o <= 16; o <<= 1) {
#pragma unroll
        for (int g = 0; g < G; g++) p[g] += __shfl_xor(p[g], o, 64);
    }
#pragma unroll
    for (int g = 0; g < G; g++) {
        float wv = __expf(p[g]);
        den += wv;
        A = pkfma(pksplat(wv), lx[g], A);
    }
}

template <bool SORTED>
__global__ __launch_bounds__(256, 5) void k_gat_agg(const float* __restrict__ xl, const float* __restrict__ xr,
                                                    const float* __restrict__ eattr,
                                                    const int* __restrict__ offs,
                                                    const int* __restrict__ seid, const int* __restrict__ ssrc,
                                                    const float* __restrict__ We, const float* __restrict__ att,
                                                    const float* __restrict__ bout,
                                                    const float* __restrict__ hin, float* __restrict__ hout, int n) {
    int wid = threadIdx.x >> 6;
    int lane = threadIdx.x & 63;
    int gwave = blockIdx.x * 4 + wid;
    const int nwaves = AGG_BLOCKS * 4;

    int chb = (lane >> 5) * 64 + (lane & 31) * 2;
    const float* xl_lane = xl + chb;

    v2f we[16];
#pragma unroll
    for (int k = 0; k < 16; k++) we[k] = *(const v2f*)&We[k * 128 + chb];
    v2f av = *(const v2f*)&att[chb];
    v2f bo = *(const v2f*)&bout[chb];

    for (int node = gwave; node < n; node += nwaves) {
        v2f xr2 = *(const v2f*)&xr[node * 128 + chb];
        int s = rfl(offs[node]);
        int e = rfl(offs[node + 1]);
        float den = 0.f;
        v2f A = pksplat(0.f);

        int j = s;
        for (; j + 8 <= e; j += 8)
            grpN<SORTED, 8>(xl_lane, eattr, seid, ssrc, j, xr2, we, av, den, A);
        if (j + 4 <= e) {
            grpN<SORTED, 4>(xl_lane, eattr, seid, ssrc, j, xr2, we, av, den, A);
            j += 4;
        }
        for (; j < e; j++)
            grpN<SORTED, 1>(xl_lane, eattr, seid, ssrc, j, xr2, we, av, den, A);

        float inv = (e > s) ? (1.f / den) : 0.f;
        v2f hg = pkfma(A, pksplat(inv), bo);
        hg = __builtin_elementwise_max(hg, pksplat(0.f));
        v2f hv = *(const v2f*)&hin[node * 128 + chb];
        *(v2f*)&hout[node * 128 + chb] = hv + hg;
    }
}

// ---------------- classifier (reads emb, writes logits only) ----------------

__global__ __launch_bounds__(256) void k_cls_lite(const float* __restrict__ emb, const float* __restrict__ Wc,
                                                  const float* __restrict__ bc, float* __restrict__ out_cls, int n) {
    int wid = threadIdx.x >> 6;
    int lane = threadIdx.x & 63;
    int node = blockIdx.x * 4 + wid;
    if (node >= n) return;
    float h0 = emb[(size_t)node * 128 + lane];
    float h1 = emb[(size_t)node * 128 + 64 + lane];
    float p[10];
#pragma unroll
    for (int k = 0; k < 10; k++) p[k] = h0 * Wc[lane * 10 + k] + h1 * Wc[(64 + lane) * 10 + k];
#pragma unroll
    for (int o = 32; o; o >>= 1) {
#pragma unroll
        for (int k = 0; k < 10; k++) p[k] += __shfl_xor(p[k], o, 64);
    }
    if (lane == 0) {
#pragma unroll
        for (int k = 0; k < 10; k++) out_cls[(size_t)node * 10 + k] = p[k] + bc[k];
    }
}

extern "C" void kernel_launch(void* const* d_in, const int* in_sizes, int n_in,
                              void* d_out, int out_size, void* d_ws, size_t ws_size,
                              hipStream_t stream) {
    const float* x         = (const float*)d_in[0];
    const int*   edge_idx  = (const int*)d_in[1];
    const float* edge_attr = (const float*)d_in[2];
    const float* Wp        = (const float*)d_in[3];
    const float* bp        = (const float*)d_in[4];
    const float* lng       = (const float*)d_in[5];
    const float* lnb       = (const float*)d_in[6];
    const float* Wl        = (const float*)d_in[7];
    const float* bl        = (const float*)d_in[8];
    const float* Wr        = (const float*)d_in[9];
    const float* br        = (const float*)d_in[10];
    const float* We        = (const float*)d_in[11];
    const float* att       = (const float*)d_in[12];
    const float* bout      = (const float*)d_in[13];
    const float* Wc        = (const float*)d_in[14];
    const float* bc        = (const float*)d_in[15];

    const int N = N_NODES, E = N_EDGES;

    char* w = (char*)d_ws;
    size_t used = 0;
    auto take = [&](size_t bytes) -> void* {
        void* p = (void*)(w + used);
        used += (bytes + 255) & ~(size_t)255;
        return p;
    };
    float* h      = (float*)take((size_t)N * 128 * 4);
    float* xl     = (float*)take((size_t)N * 128 * 4);
    float* xr     = (float*)take((size_t)N * 128 * 4);
    int*   indeg  = (int*)take((size_t)N * 4);
    int*   offs   = (int*)take((size_t)(N + 1) * 4);
    int*   cursor = (int*)take((size_t)N * 4);
    int*   bsum   = (int*)take(64 * 4);
    int*   seid   = (int*)take((size_t)E * 4);
    int*   ssrc   = (int*)take((size_t)E * 4);
    float* sea    = (float*)take((size_t)E * 16 * 4);
    bool sorted_ok = (used <= ws_size);

    float* out_cls = (float*)d_out;
    float* out_emb = (float*)d_out + (size_t)N * KCLS;

    const int* srcArr = edge_idx;
    const int* dstArr = edge_idx + E;

    (void)hipMemsetAsync(indeg, 0, (size_t)N * 4, stream);
    k_count<<<(E + 255) / 256, 256, 0, stream>>>(dstArr, indeg, E);
    int NB = (N + 1023) / 1024;
    k_scan_block<<<NB, 1024, 0, stream>>>(indeg, offs, bsum, N);
    k_scan_small<<<1, 64, 0, stream>>>(bsum, NB);
    k_scan_add<<<NB, 1024, 0, stream>>>(offs, bsum, cursor, N, E);
    if (sorted_ok)
        k_scatter_fused<<<(E + 255) / 256, 256, 0, stream>>>(srcArr, dstArr, edge_attr, cursor, ssrc, sea, E);
    else
        k_scatter<<<(E + 255) / 256, 256, 0, stream>>>(srcArr, dstArr, cursor, seid, ssrc, E);

    // layer 0: fused proj + LN + dual GEMM
    k_ln_gemm_first<<<(N + 31) / 32, 256, 0, stream>>>(
        x, Wp, bp, lng, lnb,
        Wl, bl, Wr, br, h, xl, xr, N);
    if (sorted_ok)
        k_gat_agg<true><<<AGG_BLOCKS, 256, 0, stream>>>(
            xl, xr, sea, offs, seid, ssrc, We, att, bout, h, h, N);
    else
        k_gat_agg<false><<<AGG_BLOCKS, 256, 0, stream>>>(
            xl, xr, edge_attr, offs, seid, ssrc, We, att, bout, h, h, N);

    // layer 1
    k_ln_gemm<<<(N + 31) / 32, 256, 0, stream>>>(
        h, lng + 128, lnb + 128,
        Wl + (size_t)128 * 128, bl + 128,
        Wr + (size_t)128 * 128, br + 128,
        xl, xr, N);
    if (sorted_ok)
        k_gat_agg<true><<<AGG_BLOCKS, 256, 0, stream>>>(
            xl, xr, sea, offs, seid, ssrc,
            We + 16 * 128, att + 128, bout + 128, h, out_emb, N);
    else
        k_gat_agg<false><<<AGG_BLOCKS, 256, 0, stream>>>(
            xl, xr, edge_attr, offs, seid, ssrc,
            We + 16 * 128, att + 128, bout + 128, h, out_emb, N);

    k_cls_lite<<<(N + 3) / 4, 256, 0, stream>>>(out_emb, Wc, bc, out_cls, N);
}

// Round 13
// 444.601 us; speedup vs baseline: 1.7655x; 1.0168x over previous
//
#include <hip/hip_runtime.h>
#include <math.h>

#define N_NODES 50000
#define N_EDGES 800000
#define FDIM 128
#define KCLS 10

typedef float v2f __attribute__((ext_vector_type(2)));

__device__ __forceinline__ v2f pksplat(float a) { v2f r; r.x = a; r.y = a; return r; }
__device__ __forceinline__ v2f pkfma(v2f a, v2f b, v2f c) { return __builtin_elementwise_fma(a, b, c); }
__device__ __forceinline__ v2f pklrelu(v2f v) {
    v2f z = pksplat(0.f);
    v2f mx = __builtin_elementwise_max(v, z);
    v2f mn = __builtin_elementwise_min(v, z);
    return pkfma(pksplat(0.2f), mn, mx);
}
__device__ __forceinline__ int rfl(int v) { return __builtin_amdgcn_readfirstlane(v); }

// sum over each 32-lane half, all lanes receive the result.
// Levels 1,2 via DPP quad_perm (xor), 4,8 via DPP row_ror (rotation-fold),
// 16 via ds_swizzle. 4 of 5 levels run on the VALU pipe instead of DS.
__device__ __forceinline__ float half_sum32(float x) {
    int v;
    v = __builtin_amdgcn_update_dpp(0, __float_as_int(x), 0xB1, 0xF, 0xF, true);   // quad_perm(1,0,3,2)
    x += __int_as_float(v);
    v = __builtin_amdgcn_update_dpp(0, __float_as_int(x), 0x4E, 0xF, 0xF, true);   // quad_perm(2,3,0,1)
    x += __int_as_float(v);
    v = __builtin_amdgcn_update_dpp(0, __float_as_int(x), 0x124, 0xF, 0xF, true);  // row_ror:4
    x += __int_as_float(v);
    v = __builtin_amdgcn_update_dpp(0, __float_as_int(x), 0x128, 0xF, 0xF, true);  // row_ror:8
    x += __int_as_float(v);
    v = __builtin_amdgcn_ds_swizzle(__float_as_int(x), 0x401F);                    // xor16
    x += __int_as_float(v);
    return x;
}

// ---------------- CSR build ----------------

__global__ void k_count(const int* __restrict__ dst, int* __restrict__ indeg, int e_total) {
    int e = blockIdx.x * 256 + threadIdx.x;
    if (e < e_total) atomicAdd(&indeg[dst[e]], 1);
}

__global__ __launch_bounds__(1024) void k_scan_block(const int* __restrict__ in, int* __restrict__ excl,
                                                     int* __restrict__ bsum, int n) {
    __shared__ int sh[1024];
    int t = threadIdx.x;
    int g = blockIdx.x * 1024 + t;
    int v = (g < n) ? in[g] : 0;
    sh[t] = v;
    __syncthreads();
    for (int d = 1; d < 1024; d <<= 1) {
        int x = (t >= d) ? sh[t - d] : 0;
        __syncthreads();
        sh[t] += x;
        __syncthreads();
    }
    if (g < n) excl[g] = sh[t] - v;
    if (t == 1023) bsum[blockIdx.x] = sh[t];
}

__global__ void k_scan_small(int* bsum, int nb) {
    if (threadIdx.x == 0 && blockIdx.x == 0) {
        int run = 0;
        for (int i = 0; i < nb; i++) { int v = bsum[i]; bsum[i] = run; run += v; }
    }
}

__global__ __launch_bounds__(1024) void k_scan_add(int* __restrict__ offs, const int* __restrict__ bsum,
                                                   int* __restrict__ cursor, int n, int e_total) {
    int g = blockIdx.x * 1024 + threadIdx.x;
    if (g < n) {
        int v = offs[g] + bsum[blockIdx.x];
        offs[g] = v;
        cursor[g] = v;
    }
    if (g == 0) offs[n] = e_total;
}

__global__ void k_scatter_fused(const int* __restrict__ src, const int* __restrict__ dst,
                                const float* __restrict__ edge_attr,
                                int* __restrict__ cursor, int* __restrict__ ssrc,
                                float* __restrict__ sea, int e_total) {
    int e = blockIdx.x * 256 + threadIdx.x;
    if (e < e_total) {
        int d = dst[e];
        int p = atomicAdd(&cursor[d], 1);
        ssrc[p] = src[e];
        const float4* ea = (const float4*)&edge_attr[(size_t)e * 16];
        float4* out = (float4*)&sea[(size_t)p * 16];
        float4 a = ea[0], b = ea[1], c = ea[2], q = ea[3];
        out[0] = a; out[1] = b; out[2] = c; out[3] = q;
    }
}

__global__ void k_scatter(const int* __restrict__ src, const int* __restrict__ dst,
                          int* __restrict__ cursor, int* __restrict__ seid, int* __restrict__ ssrc, int e_total) {
    int e = blockIdx.x * 256 + threadIdx.x;
    if (e < e_total) {
        int d = dst[e];
        int p = atomicAdd(&cursor[d], 1);
        seid[p] = e;
        ssrc[p] = src[e];
    }
}

// ---------------- layer-0 fused: h = x@Wp+bp; LN(h); xl/xr dual GEMM ----------------

__global__ __launch_bounds__(256) void k_ln_gemm_first(const float* __restrict__ x, const float* __restrict__ Wp,
                                                       const float* __restrict__ bp,
                                                       const float* __restrict__ lng, const float* __restrict__ lnb,
                                                       const float* __restrict__ Wl, const float* __restrict__ bl,
                                                       const float* __restrict__ Wr, const float* __restrict__ br,
                                                       float* __restrict__ h, float* __restrict__ xl,
                                                       float* __restrict__ xr, int n) {
    __shared__ float u[10240];
    __shared__ float shn[4096];
    __shared__ float smu[32], srs[32];
    int t = threadIdx.x;
    int row0 = blockIdx.x * 32;
    int nrows = min(32, n - row0);
    float* shx = u;
    float* shwp = u + 2048;

    for (int i = t; i < 2048; i += 256)
        ((float4*)shwp)[i] = ((const float4*)Wp)[i];
    for (int i = t; i < 512; i += 256) {
        int r = i >> 4;
        float4 v = make_float4(0.f, 0.f, 0.f, 0.f);
        if (r < nrows) v = ((const float4*)x)[row0 * 16 + i];
        ((float4*)shx)[i] = v;
    }
    __syncthreads();

    int tr = (t >> 5) * 4;
    int tc = (t & 31) * 4;
    {
        float acc[4][4];
        float4 b4 = *(const float4*)&bp[tc];
#pragma unroll
        for (int j = 0; j < 4; j++) { acc[j][0] = b4.x; acc[j][1] = b4.y; acc[j][2] = b4.z; acc[j][3] = b4.w; }
        for (int k = 0; k < 64; k++) {
            float4 w = *(float4*)&shwp[k * 128 + tc];
#pragma unroll
            for (int j = 0; j < 4; j++) {
                float a = shx[(tr + j) * 64 + k];
                acc[j][0] = fmaf(a, w.x, acc[j][0]);
                acc[j][1] = fmaf(a, w.y, acc[j][1]);
                acc[j][2] = fmaf(a, w.z, acc[j][2]);
                acc[j][3] = fmaf(a, w.w, acc[j][3]);
            }
        }
#pragma unroll
        for (int j = 0; j < 4; j++) {
            int r = row0 + tr + j;
            float4 o = make_float4(acc[j][0], acc[j][1], acc[j][2], acc[j][3]);
            *(float4*)&shn[(tr + j) * 128 + tc] = o;
            if (r < n) *(float4*)&h[r * 128 + tc] = o;
        }
    }
    __syncthreads();

    {
        int r = t >> 3, sl = t & 7;
        float s = 0.f, ss = 0.f;
        for (int c = sl; c < 128; c += 8) {
            float v = shn[r * 128 + c];
            s += v; ss += v * v;
        }
#pragma unroll
        for (int o = 1; o < 8; o <<= 1) { s += __shfl_xor(s, o, 64); ss += __shfl_xor(ss, o, 64); }
        if (sl == 0) {
            float mu = s * (1.f / 128.f);
            float var = ss * (1.f / 128.f) - mu * mu;
            smu[r] = mu;
            srs[r] = rsqrtf(var + 1e-5f);
        }
    }
    __syncthreads();
    for (int i = t; i < 4096; i += 256) {
        int r = i >> 7, c = i & 127;
        shn[i] = (shn[i] - smu[r]) * srs[r] * lng[c] + lnb[c];
    }

    float accl[4][4], accr[4][4];
    {
        float4 bl4 = *(const float4*)&bl[tc];
        float4 br4 = *(const float4*)&br[tc];
#pragma unroll
        for (int j = 0; j < 4; j++) {
            accl[j][0] = bl4.x; accl[j][1] = bl4.y; accl[j][2] = bl4.z; accl[j][3] = bl4.w;
            accr[j][0] = br4.x; accr[j][1] = br4.y; accr[j][2] = br4.z; accr[j][3] = br4.w;
        }
    }
    float* shwl = u;
    float* shwr = u + 4096;

    for (int kb = 0; kb < 4; kb++) {
        __syncthreads();
        for (int i = t; i < 1024; i += 256) {
            ((float4*)shwl)[i] = ((const float4*)Wl)[kb * 1024 + i];
            ((float4*)shwr)[i] = ((const float4*)Wr)[kb * 1024 + i];
        }
        __syncthreads();
#pragma unroll 8
        for (int kk = 0; kk < 32; kk++) {
            int k = kb * 32 + kk;
            float4 wl4 = *(float4*)&shwl[kk * 128 + tc];
            float4 wr4 = *(float4*)&shwr[kk * 128 + tc];
#pragma unroll
            for (int j = 0; j < 4; j++) {
                float a = shn[(tr + j) * 128 + k];
                accl[j][0] = fmaf(a, wl4.x, accl[j][0]);
                accl[j][1] = fmaf(a, wl4.y, accl[j][1]);
                accl[j][2] = fmaf(a, wl4.z, accl[j][2]);
                accl[j][3] = fmaf(a, wl4.w, accl[j][3]);
                accr[j][0] = fmaf(a, wr4.x, accr[j][0]);
                accr[j][1] = fmaf(a, wr4.y, accr[j][1]);
                accr[j][2] = fmaf(a, wr4.z, accr[j][2]);
                accr[j][3] = fmaf(a, wr4.w, accr[j][3]);
            }
        }
    }
#pragma unroll
    for (int j = 0; j < 4; j++) {
        int r = row0 + tr + j;
        if (r < n) {
            float4 ol = make_float4(accl[j][0], accl[j][1], accl[j][2], accl[j][3]);
            float4 orr = make_float4(accr[j][0], accr[j][1], accr[j][2], accr[j][3]);
            *(float4*)&xl[r * 128 + tc] = ol;
            *(float4*)&xr[r * 128 + tc] = orr;
        }
    }
}

// ---------------- layer-1 LayerNorm + dual GEMM ----------------

__global__ __launch_bounds__(256) void k_ln_gemm(const float* __restrict__ h,
                                                 const float* __restrict__ lng, const float* __restrict__ lnb,
                                                 const float* __restrict__ Wl, const float* __restrict__ bl,
                                                 const float* __restrict__ Wr, const float* __restrict__ br,
                                                 float* __restrict__ xl, float* __restrict__ xr, int n) {
    __shared__ float shn[32 * 128];
    __shared__ float shwl[32 * 128];
    __shared__ float shwr[32 * 128];
    __shared__ float smu[32], srs[32];
    int t = threadIdx.x;
    int row0 = blockIdx.x * 32;
    int nrows = min(32, n - row0);

    for (int i = t; i < 1024; i += 256) {
        int r = i >> 5;
        float4 v = make_float4(0.f, 0.f, 0.f, 0.f);
        if (r < nrows) v = ((const float4*)h)[row0 * 32 + i];
        ((float4*)shn)[i] = v;
    }
    __syncthreads();

    {
        int r = t >> 3, sl = t & 7;
        float s = 0.f, ss = 0.f;
        for (int c = sl; c < 128; c += 8) {
            float v = shn[r * 128 + c];
            s += v; ss += v * v;
        }
#pragma unroll
        for (int o = 1; o < 8; o <<= 1) { s += __shfl_xor(s, o, 64); ss += __shfl_xor(ss, o, 64); }
        if (sl == 0) {
            float mu = s * (1.f / 128.f);
            float var = ss * (1.f / 128.f) - mu * mu;
            smu[r] = mu;
            srs[r] = rsqrtf(var + 1e-5f);
        }
    }
    __syncthreads();
    for (int i = t; i < 4096; i += 256) {
        int r = i >> 7, c = i & 127;
        shn[i] = (shn[i] - smu[r]) * srs[r] * lng[c] + lnb[c];
    }

    int tr = (t >> 5) * 4;
    int tc = (t & 31) * 4;
    float accl[4][4], accr[4][4];
    {
        float4 bl4 = *(const float4*)&bl[tc];
        float4 br4 = *(const float4*)&br[tc];
#pragma unroll
        for (int j = 0; j < 4; j++) {
            accl[j][0] = bl4.x; accl[j][1] = bl4.y; accl[j][2] = bl4.z; accl[j][3] = bl4.w;
            accr[j][0] = br4.x; accr[j][1] = br4.y; accr[j][2] = br4.z; accr[j][3] = br4.w;
        }
    }

    for (int kb = 0; kb < 4; kb++) {
        __syncthreads();
        for (int i = t; i < 1024; i += 256) {
            ((float4*)shwl)[i] = ((const float4*)Wl)[kb * 1024 + i];
            ((float4*)shwr)[i] = ((const float4*)Wr)[kb * 1024 + i];
        }
        __syncthreads();
#pragma unroll 8
        for (int kk = 0; kk < 32; kk++) {
            int k = kb * 32 + kk;
            float4 wl4 = *(float4*)&shwl[kk * 128 + tc];
            float4 wr4 = *(float4*)&shwr[kk * 128 + tc];
#pragma unroll
            for (int j = 0; j < 4; j++) {
                float a = shn[(tr + j) * 128 + k];
                accl[j][0] = fmaf(a, wl4.x, accl[j][0]);
                accl[j][1] = fmaf(a, wl4.y, accl[j][1]);
                accl[j][2] = fmaf(a, wl4.z, accl[j][2]);
                accl[j][3] = fmaf(a, wl4.w, accl[j][3]);
                accr[j][0] = fmaf(a, wr4.x, accr[j][0]);
                accr[j][1] = fmaf(a, wr4.y, accr[j][1]);
                accr[j][2] = fmaf(a, wr4.z, accr[j][2]);
                accr[j][3] = fmaf(a, wr4.w, accr[j][3]);
            }
        }
    }
#pragma unroll
    for (int j = 0; j < 4; j++) {
        int r = row0 + tr + j;
        if (r < n) {
            float4 ol = make_float4(accl[j][0], accl[j][1], accl[j][2], accl[j][3]);
            float4 orr = make_float4(accr[j][0], accr[j][1], accr[j][2], accr[j][3]);
            *(float4*)&xl[r * 128 + tc] = ol;
            *(float4*)&xr[r * 128 + tc] = orr;
        }
    }
}

// ---------------- GAT aggregate (lb(256,5), 1280 blocks, G=8, DPP reduction) ----------------
// 64-VGPR budgets (>=6 waves/EU) spill this kernel (R7/R8/R10) -- keep 102.

#define AGG_BLOCKS 1280

template <bool SORTED, int G>
__device__ __forceinline__ void grpN(const float* __restrict__ xl_lane, const float* __restrict__ eattr,
                                     const int* __restrict__ seid, const int* __restrict__ ssrc,
                                     int j, v2f xr2, const v2f* we, v2f av,
                                     float& den, v2f& A) {
    v2f lx[G];
    const float* ep[G];
#pragma unroll
    for (int g = 0; g < G; g++) {
        int sn = rfl(ssrc[j + g]);
        lx[g] = *(const v2f*)(xl_lane + sn * 128);
        int r = SORTED ? (j + g) : rfl(seid[j + g]);
        ep[g] = &eattr[(size_t)r * 16];
    }
    v2f v[G];
#pragma unroll
    for (int g = 0; g < G; g++) v[g] = lx[g] + xr2;
#pragma unroll
    for (int k = 0; k < 16; k++) {
#pragma unroll
        for (int g = 0; g < G; g++) v[g] = pkfma(pksplat(ep[g][k]), we[k], v[g]);
    }
    float p[G];
#pragma unroll
    for (int g = 0; g < G; g++) {
        v2f t = pklrelu(v[g]) * av;
        p[g] = t.x + t.y;
    }
#pragma unroll
    for (int g = 0; g < G; g++) p[g] = half_sum32(p[g]);
#pragma unroll
    for (int g = 0; g < G; g++) {
        float wv = __expf(p[g]);
        den += wv;
        A = pkfma(pksplat(wv), lx[g], A);
    }
}

template <bool SORTED>
__global__ __launch_bounds__(256, 5) void k_gat_agg(const float* __restrict__ xl, const float* __restrict__ xr,
                                                    const float* __restrict__ eattr,
                                                    const int* __restrict__ offs,
                                                    const int* __restrict__ seid, const int* __restrict__ ssrc,
                                                    const float* __restrict__ We, const float* __restrict__ att,
                                                    const float* __restrict__ bout,
                                                    const float* __restrict__ hin, float* __restrict__ hout, int n) {
    int wid = threadIdx.x >> 6;
    int lane = threadIdx.x & 63;
    int gwave = blockIdx.x * 4 + wid;
    const int nwaves = AGG_BLOCKS * 4;

    int chb = (lane >> 5) * 64 + (lane & 31) * 2;
    const float* xl_lane = xl + chb;

    v2f we[16];
#pragma unroll
    for (int k = 0; k < 16; k++) we[k] = *(const v2f*)&We[k * 128 + chb];
    v2f av = *(const v2f*)&att[chb];
    v2f bo = *(const v2f*)&bout[chb];

    for (int node = gwave; node < n; node += nwaves) {
        v2f xr2 = *(const v2f*)&xr[node * 128 + chb];
        int s = rfl(offs[node]);
        int e = rfl(offs[node + 1]);
        float den = 0.f;
        v2f A = pksplat(0.f);

        int j = s;
        for (; j + 8 <= e; j += 8)
            grpN<SORTED, 8>(xl_lane, eattr, seid, ssrc, j, xr2, we, av, den, A);
        if (j + 4 <= e) {
            grpN<SORTED, 4>(xl_lane, eattr, seid, ssrc, j, xr2, we, av, den, A);
            j += 4;
        }
        for (; j < e; j++)
            grpN<SORTED, 1>(xl_lane, eattr, seid, ssrc, j, xr2, we, av, den, A);

        float inv = (e > s) ? (1.f / den) : 0.f;
        v2f hg = pkfma(A, pksplat(inv), bo);
        hg = __builtin_elementwise_max(hg, pksplat(0.f));
        v2f hv = *(const v2f*)&hin[node * 128 + chb];
        *(v2f*)&hout[node * 128 + chb] = hv + hg;
    }
}

// ---------------- classifier ----------------

__global__ __launch_bounds__(256) void k_cls_lite(const float* __restrict__ emb, const float* __restrict__ Wc,
                                                  const float* __restrict__ bc, float* __restrict__ out_cls, int n) {
    int wid = threadIdx.x >> 6;
    int lane = threadIdx.x & 63;
    int node = blockIdx.x * 4 + wid;
    if (node >= n) return;
    float h0 = emb[(size_t)node * 128 + lane];
    float h1 = emb[(size_t)node * 128 + 64 + lane];
    float p[10];
#pragma unroll
    for (int k = 0; k < 10; k++) p[k] = h0 * Wc[lane * 10 + k] + h1 * Wc[(64 + lane) * 10 + k];
#pragma unroll
    for (int o = 32; o; o >>= 1) {
#pragma unroll
        for (int k = 0; k < 10; k++) p[k] += __shfl_xor(p[k], o, 64);
    }
    if (lane == 0) {
#pragma unroll
        for (int k = 0; k < 10; k++) out_cls[(size_t)node * 10 + k] = p[k] + bc[k];
    }
}

extern "C" void kernel_launch(void* const* d_in, const int* in_sizes, int n_in,
                              void* d_out, int out_size, void* d_ws, size_t ws_size,
                              hipStream_t stream) {
    const float* x         = (const float*)d_in[0];
    const int*   edge_idx  = (const int*)d_in[1];
    const float* edge_attr = (const float*)d_in[2];
    const float* Wp        = (const float*)d_in[3];
    const float* bp        = (const float*)d_in[4];
    const float* lng       = (const float*)d_in[5];
    const float* lnb       = (const float*)d_in[6];
    const float* Wl        = (const float*)d_in[7];
    const float* bl        = (const float*)d_in[8];
    const float* Wr        = (const float*)d_in[9];
    const float* br        = (const float*)d_in[10];
    const float* We        = (const float*)d_in[11];
    const float* att       = (const float*)d_in[12];
    const float* bout      = (const float*)d_in[13];
    const float* Wc        = (const float*)d_in[14];
    const float* bc        = (const float*)d_in[15];

    const int N = N_NODES, E = N_EDGES;

    char* w = (char*)d_ws;
    size_t used = 0;
    auto take = [&](size_t bytes) -> void* {
        void* p = (void*)(w + used);
        used += (bytes + 255) & ~(size_t)255;
        return p;
    };
    float* h      = (float*)take((size_t)N * 128 * 4);
    float* xl     = (float*)take((size_t)N * 128 * 4);
    float* xr     = (float*)take((size_t)N * 128 * 4);
    int*   indeg  = (int*)take((size_t)N * 4);
    int*   offs   = (int*)take((size_t)(N + 1) * 4);
    int*   cursor = (int*)take((size_t)N * 4);
    int*   bsum   = (int*)take(64 * 4);
    int*   seid   = (int*)take((size_t)E * 4);
    int*   ssrc   = (int*)take((size_t)E * 4);
    float* sea    = (float*)take((size_t)E * 16 * 4);
    bool sorted_ok = (used <= ws_size);

    float* out_cls = (float*)d_out;
    float* out_emb = (float*)d_out + (size_t)N * KCLS;

    const int* srcArr = edge_idx;
    const int* dstArr = edge_idx + E;

    (void)hipMemsetAsync(indeg, 0, (size_t)N * 4, stream);
    k_count<<<(E + 255) / 256, 256, 0, stream>>>(dstArr, indeg, E);
    int NB = (N + 1023) / 1024;
    k_scan_block<<<NB, 1024, 0, stream>>>(indeg, offs, bsum, N);
    k_scan_small<<<1, 64, 0, stream>>>(bsum, NB);
    k_scan_add<<<NB, 1024, 0, stream>>>(offs, bsum, cursor, N, E);
    if (sorted_ok)
        k_scatter_fused<<<(E + 255) / 256, 256, 0, stream>>>(srcArr, dstArr, edge_attr, cursor, ssrc, sea, E);
    else
        k_scatter<<<(E + 255) / 256, 256, 0, stream>>>(srcArr, dstArr, cursor, seid, ssrc, E);

    k_ln_gemm_first<<<(N + 31) / 32, 256, 0, stream>>>(
        x, Wp, bp, lng, lnb,
        Wl, bl, Wr, br, h, xl, xr, N);
    if (sorted_ok)
        k_gat_agg<true><<<AGG_BLOCKS, 256, 0, stream>>>(
            xl, xr, sea, offs, seid, ssrc, We, att, bout, h, h, N);
    else
        k_gat_agg<false><<<AGG_BLOCKS, 256, 0, stream>>>(
            xl, xr, edge_attr, offs, seid, ssrc, We, att, bout, h, h, N);

    k_ln_gemm<<<(N + 31) / 32, 256, 0, stream>>>(
        h, lng + 128, lnb + 128,
        Wl + (size_t)128 * 128, bl + 128,
        Wr + (size_t)128 * 128, br + 128,
        xl, xr, N);
    if (sorted_ok)
        k_gat_agg<true><<<AGG_BLOCKS, 256, 0, stream>>>(
            xl, xr, sea, offs, seid, ssrc,
            We + 16 * 128, att + 128, bout + 128, h, out_emb, N);
    else
        k_gat_agg<false><<<AGG_BLOCKS, 256, 0, stream>>>(
            xl, xr, edge_attr, offs, seid, ssrc,
            We + 16 * 128, att + 128, bout + 128, h, out_emb, N);

    k_cls_lite<<<(N + 3) / 4, 256, 0, stream>>>(out_emb, Wc, bc, out_cls, N);
}

// Round 14
// 442.044 us; speedup vs baseline: 1.7757x; 1.0058x over previous
//
#include <hip/hip_runtime.h>
#include <math.h>

#define N_NODES 50000
#define N_EDGES 800000
#define FDIM 128
#define KCLS 10

typedef float v2f __attribute__((ext_vector_type(2)));

__device__ __forceinline__ v2f pksplat(float a) { v2f r; r.x = a; r.y = a; return r; }
__device__ __forceinline__ v2f pkfma(v2f a, v2f b, v2f c) { return __builtin_elementwise_fma(a, b, c); }
__device__ __forceinline__ v2f pklrelu(v2f v) {
    v2f z = pksplat(0.f);
    v2f mx = __builtin_elementwise_max(v, z);
    v2f mn = __builtin_elementwise_min(v, z);
    return pkfma(pksplat(0.2f), mn, mx);
}
__device__ __forceinline__ int rfl(int v) { return __builtin_amdgcn_readfirstlane(v); }

// sum over each 32-lane half, all lanes receive the result.
__device__ __forceinline__ float half_sum32(float x) {
    int v;
    v = __builtin_amdgcn_update_dpp(0, __float_as_int(x), 0xB1, 0xF, 0xF, true);   // quad_perm(1,0,3,2)
    x += __int_as_float(v);
    v = __builtin_amdgcn_update_dpp(0, __float_as_int(x), 0x4E, 0xF, 0xF, true);   // quad_perm(2,3,0,1)
    x += __int_as_float(v);
    v = __builtin_amdgcn_update_dpp(0, __float_as_int(x), 0x124, 0xF, 0xF, true);  // row_ror:4
    x += __int_as_float(v);
    v = __builtin_amdgcn_update_dpp(0, __float_as_int(x), 0x128, 0xF, 0xF, true);  // row_ror:8
    x += __int_as_float(v);
    v = __builtin_amdgcn_ds_swizzle(__float_as_int(x), 0x401F);                    // xor16
    x += __int_as_float(v);
    return x;
}

// ---------------- CSR build ----------------

__global__ void k_count(const int* __restrict__ dst, int* __restrict__ indeg, int e_total) {
    int e = blockIdx.x * 256 + threadIdx.x;
    if (e < e_total) atomicAdd(&indeg[dst[e]], 1);
}

__global__ __launch_bounds__(1024) void k_scan_block(const int* __restrict__ in, int* __restrict__ excl,
                                                     int* __restrict__ bsum, int n) {
    __shared__ int sh[1024];
    int t = threadIdx.x;
    int g = blockIdx.x * 1024 + t;
    int v = (g < n) ? in[g] : 0;
    sh[t] = v;
    __syncthreads();
    for (int d = 1; d < 1024; d <<= 1) {
        int x = (t >= d) ? sh[t - d] : 0;
        __syncthreads();
        sh[t] += x;
        __syncthreads();
    }
    if (g < n) excl[g] = sh[t] - v;
    if (t == 1023) bsum[blockIdx.x] = sh[t];
}

__global__ void k_scan_small(int* bsum, int nb) {
    if (threadIdx.x == 0 && blockIdx.x == 0) {
        int run = 0;
        for (int i = 0; i < nb; i++) { int v = bsum[i]; bsum[i] = run; run += v; }
    }
}

__global__ __launch_bounds__(1024) void k_scan_add(int* __restrict__ offs, const int* __restrict__ bsum,
                                                   int* __restrict__ cursor, int n, int e_total) {
    int g = blockIdx.x * 1024 + threadIdx.x;
    if (g < n) {
        int v = offs[g] + bsum[blockIdx.x];
        offs[g] = v;
        cursor[g] = v;
    }
    if (g == 0) offs[n] = e_total;
}

__global__ void k_scatter_fused(const int* __restrict__ src, const int* __restrict__ dst,
                                const float* __restrict__ edge_attr,
                                int* __restrict__ cursor, int* __restrict__ ssrc,
                                float* __restrict__ sea, int e_total) {
    int e = blockIdx.x * 256 + threadIdx.x;
    if (e < e_total) {
        int d = dst[e];
        int p = atomicAdd(&cursor[d], 1);
        ssrc[p] = src[e];
        const float4* ea = (const float4*)&edge_attr[(size_t)e * 16];
        float4* out = (float4*)&sea[(size_t)p * 16];
        float4 a = ea[0], b = ea[1], c = ea[2], q = ea[3];
        out[0] = a; out[1] = b; out[2] = c; out[3] = q;
    }
}

__global__ void k_scatter(const int* __restrict__ src, const int* __restrict__ dst,
                          int* __restrict__ cursor, int* __restrict__ seid, int* __restrict__ ssrc, int e_total) {
    int e = blockIdx.x * 256 + threadIdx.x;
    if (e < e_total) {
        int d = dst[e];
        int p = atomicAdd(&cursor[d], 1);
        seid[p] = e;
        ssrc[p] = src[e];
    }
}

// ---------------- shared GEMM helper: acc[4][4] over one weight matrix ----------------
// shn: [32][128] normalized activations; W staged in 16KB chunks of 32 k-rows.

__device__ __forceinline__ void gemm_pass(const float* __restrict__ W, const float* __restrict__ bias,
                                          float* __restrict__ shw, const float* __restrict__ shn,
                                          int t, int tr, int tc, float acc[4][4]) {
    float4 b4 = *(const float4*)&bias[tc];
#pragma unroll
    for (int j = 0; j < 4; j++) { acc[j][0] = b4.x; acc[j][1] = b4.y; acc[j][2] = b4.z; acc[j][3] = b4.w; }
    for (int kb = 0; kb < 4; kb++) {
        __syncthreads();
        for (int i = t; i < 1024; i += 256)
            ((float4*)shw)[i] = ((const float4*)W)[kb * 1024 + i];
        __syncthreads();
#pragma unroll 8
        for (int kk = 0; kk < 32; kk++) {
            int k = kb * 32 + kk;
            float4 w4 = *(float4*)&shw[kk * 128 + tc];
#pragma unroll
            for (int j = 0; j < 4; j++) {
                float a = shn[(tr + j) * 128 + k];
                acc[j][0] = fmaf(a, w4.x, acc[j][0]);
                acc[j][1] = fmaf(a, w4.y, acc[j][1]);
                acc[j][2] = fmaf(a, w4.z, acc[j][2]);
                acc[j][3] = fmaf(a, w4.w, acc[j][3]);
            }
        }
    }
}

// normalize reg-tile rows via half-wave DPP reduce, write normalized into shn
__device__ __forceinline__ void ln_to_shn(float a0[4][4], const float* __restrict__ lng,
                                          const float* __restrict__ lnb, float* __restrict__ shn,
                                          int tr, int tc) {
    float4 g4 = *(const float4*)&lng[tc];
    float4 b4 = *(const float4*)&lnb[tc];
#pragma unroll
    for (int j = 0; j < 4; j++) {
        float s = (a0[j][0] + a0[j][1]) + (a0[j][2] + a0[j][3]);
        float ss = a0[j][0] * a0[j][0] + a0[j][1] * a0[j][1] + a0[j][2] * a0[j][2] + a0[j][3] * a0[j][3];
        s = half_sum32(s);
        ss = half_sum32(ss);
        float mu = s * (1.f / 128.f);
        float var = ss * (1.f / 128.f) - mu * mu;
        float rs = rsqrtf(var + 1e-5f);
        float4 o;
        o.x = (a0[j][0] - mu) * rs * g4.x + b4.x;
        o.y = (a0[j][1] - mu) * rs * g4.y + b4.y;
        o.z = (a0[j][2] - mu) * rs * g4.z + b4.z;
        o.w = (a0[j][3] - mu) * rs * g4.w + b4.w;
        *(float4*)&shn[(tr + j) * 128 + tc] = o;
    }
}

// ---------------- layer-0 fused: proj + LN + dual GEMM (32KB LDS) ----------------

__global__ __launch_bounds__(256) void k_ln_gemm_first(const float* __restrict__ x, const float* __restrict__ Wp,
                                                       const float* __restrict__ bp,
                                                       const float* __restrict__ lng, const float* __restrict__ lnb,
                                                       const float* __restrict__ Wl, const float* __restrict__ bl,
                                                       const float* __restrict__ Wr, const float* __restrict__ br,
                                                       float* __restrict__ h, float* __restrict__ xl,
                                                       float* __restrict__ xr, int n) {
    __shared__ float shn[4096];  // 16 KB: phase0 = shx (first 2048), later normalized tile
    __shared__ float shw[4096];  // 16 KB weight chunk
    int t = threadIdx.x;
    int row0 = blockIdx.x * 32;
    int nrows = min(32, n - row0);
    int tr = (t >> 5) * 4;
    int tc = (t & 31) * 4;
    float* shx = shn;  // 32x64 x-tile aliases shn (safe: sync before overwrite)

    for (int i = t; i < 512; i += 256) {
        int r = i >> 4;
        float4 v = make_float4(0.f, 0.f, 0.f, 0.f);
        if (r < nrows) v = ((const float4*)x)[row0 * 16 + i];
        ((float4*)shx)[i] = v;
    }

    // proj: acc = x @ Wp + bp, Wp staged in 2 chunks of 32 k-rows
    float a0[4][4];
    {
        float4 b4 = *(const float4*)&bp[tc];
#pragma unroll
        for (int j = 0; j < 4; j++) { a0[j][0] = b4.x; a0[j][1] = b4.y; a0[j][2] = b4.z; a0[j][3] = b4.w; }
        for (int kb = 0; kb < 2; kb++) {
            __syncthreads();
            for (int i = t; i < 1024; i += 256)
                ((float4*)shw)[i] = ((const float4*)Wp)[kb * 1024 + i];
            __syncthreads();
#pragma unroll 8
            for (int kk = 0; kk < 32; kk++) {
                int k = kb * 32 + kk;
                float4 w4 = *(float4*)&shw[kk * 128 + tc];
#pragma unroll
                for (int j = 0; j < 4; j++) {
                    float a = shx[(tr + j) * 64 + k];
                    a0[j][0] = fmaf(a, w4.x, a0[j][0]);
                    a0[j][1] = fmaf(a, w4.y, a0[j][1]);
                    a0[j][2] = fmaf(a, w4.z, a0[j][2]);
                    a0[j][3] = fmaf(a, w4.w, a0[j][3]);
                }
            }
        }
    }
    __syncthreads();  // all shx reads done; safe to overwrite shn

    // write raw h; write normalized tile into shn (LN stats via DPP half-wave reduce)
#pragma unroll
    for (int j = 0; j < 4; j++) {
        int r = row0 + tr + j;
        if (r < n) *(float4*)&h[r * 128 + tc] = make_float4(a0[j][0], a0[j][1], a0[j][2], a0[j][3]);
    }
    ln_to_shn(a0, lng, lnb, shn, tr, tc);

    float acc[4][4];
    gemm_pass(Wl, bl, shw, shn, t, tr, tc, acc);
#pragma unroll
    for (int j = 0; j < 4; j++) {
        int r = row0 + tr + j;
        if (r < n) *(float4*)&xl[r * 128 + tc] = make_float4(acc[j][0], acc[j][1], acc[j][2], acc[j][3]);
    }
    gemm_pass(Wr, br, shw, shn, t, tr, tc, acc);
#pragma unroll
    for (int j = 0; j < 4; j++) {
        int r = row0 + tr + j;
        if (r < n) *(float4*)&xr[r * 128 + tc] = make_float4(acc[j][0], acc[j][1], acc[j][2], acc[j][3]);
    }
}

// ---------------- layer-1 LN + dual GEMM (32KB LDS, reg-tile LN) ----------------

__global__ __launch_bounds__(256) void k_ln_gemm(const float* __restrict__ h,
                                                 const float* __restrict__ lng, const float* __restrict__ lnb,
                                                 const float* __restrict__ Wl, const float* __restrict__ bl,
                                                 const float* __restrict__ Wr, const float* __restrict__ br,
                                                 float* __restrict__ xl, float* __restrict__ xr, int n) {
    __shared__ float shn[4096];  // 16 KB
    __shared__ float shw[4096];  // 16 KB
    int t = threadIdx.x;
    int row0 = blockIdx.x * 32;
    int tr = (t >> 5) * 4;
    int tc = (t & 31) * 4;

    // load 4x4 reg tile directly from global
    float a0[4][4];
#pragma unroll
    for (int j = 0; j < 4; j++) {
        int r = row0 + tr + j;
        float4 v = make_float4(0.f, 0.f, 0.f, 0.f);
        if (r < n) v = *(const float4*)&h[(size_t)r * 128 + tc];
        a0[j][0] = v.x; a0[j][1] = v.y; a0[j][2] = v.z; a0[j][3] = v.w;
    }
    ln_to_shn(a0, lng, lnb, shn, tr, tc);

    float acc[4][4];
    gemm_pass(Wl, bl, shw, shn, t, tr, tc, acc);
#pragma unroll
    for (int j = 0; j < 4; j++) {
        int r = row0 + tr + j;
        if (r < n) *(float4*)&xl[r * 128 + tc] = make_float4(acc[j][0], acc[j][1], acc[j][2], acc[j][3]);
    }
    gemm_pass(Wr, br, shw, shn, t, tr, tc, acc);
#pragma unroll
    for (int j = 0; j < 4; j++) {
        int r = row0 + tr + j;
        if (r < n) *(float4*)&xr[r * 128 + tc] = make_float4(acc[j][0], acc[j][1], acc[j][2], acc[j][3]);
    }
}

// ---------------- GAT aggregate (lb(256,5), 1280 blocks, G=8, DPP reduction) ----------------
// 64-VGPR budgets (>=6 waves/EU) spill this kernel (R7/R8/R10) -- keep 102.

#define AGG_BLOCKS 1280

template <bool SORTED, int G>
__device__ __forceinline__ void grpN(const float* __restrict__ xl_lane, const float* __restrict__ eattr,
                                     const int* __restrict__ seid, const int* __restrict__ ssrc,
                                     int j, v2f xr2, const v2f* we, v2f av,
                                     float& den, v2f& A) {
    v2f lx[G];
    const float* ep[G];
#pragma unroll
    for (int g = 0; g < G; g++) {
        int sn = rfl(ssrc[j + g]);
        lx[g] = *(const v2f*)(xl_lane + sn * 128);
        int r = SORTED ? (j + g) : rfl(seid[j + g]);
        ep[g] = &eattr[(size_t)r * 16];
    }
    v2f v[G];
#pragma unroll
    for (int g = 0; g < G; g++) v[g] = lx[g] + xr2;
#pragma unroll
    for (int k = 0; k < 16; k++) {
#pragma unroll
        for (int g = 0; g < G; g++) v[g] = pkfma(pksplat(ep[g][k]), we[k], v[g]);
    }
    float p[G];
#pragma unroll
    for (int g = 0; g < G; g++) {
        v2f t = pklrelu(v[g]) * av;
        p[g] = t.x + t.y;
    }
#pragma unroll
    for (int g = 0; g < G; g++) p[g] = half_sum32(p[g]);
#pragma unroll
    for (int g = 0; g < G; g++) {
        float wv = __expf(p[g]);
        den += wv;
        A = pkfma(pksplat(wv), lx[g], A);
    }
}

template <bool SORTED>
__global__ __launch_bounds__(256, 5) void k_gat_agg(const float* __restrict__ xl, const float* __restrict__ xr,
                                                    const float* __restrict__ eattr,
                                                    const int* __restrict__ offs,
                                                    const int* __restrict__ seid, const int* __restrict__ ssrc,
                                                    const float* __restrict__ We, const float* __restrict__ att,
                                                    const float* __restrict__ bout,
                                                    const float* __restrict__ hin, float* __restrict__ hout, int n) {
    int wid = threadIdx.x >> 6;
    int lane = threadIdx.x & 63;
    int gwave = blockIdx.x * 4 + wid;
    const int nwaves = AGG_BLOCKS * 4;

    int chb = (lane >> 5) * 64 + (lane & 31) * 2;
    const float* xl_lane = xl + chb;

    v2f we[16];
#pragma unroll
    for (int k = 0; k < 16; k++) we[k] = *(const v2f*)&We[k * 128 + chb];
    v2f av = *(const v2f*)&att[chb];
    v2f bo = *(const v2f*)&bout[chb];

    for (int node = gwave; node < n; node += nwaves) {
        v2f xr2 = *(const v2f*)&xr[node * 128 + chb];
        int s = rfl(offs[node]);
        int e = rfl(offs[node + 1]);
        float den = 0.f;
        v2f A = pksplat(0.f);

        int j = s;
        for (; j + 8 <= e; j += 8)
            grpN<SORTED, 8>(xl_lane, eattr, seid, ssrc, j, xr2, we, av, den, A);
        if (j + 4 <= e) {
            grpN<SORTED, 4>(xl_lane, eattr, seid, ssrc, j, xr2, we, av, den, A);
            j += 4;
        }
        for (; j < e; j++)
            grpN<SORTED, 1>(xl_lane, eattr, seid, ssrc, j, xr2, we, av, den, A);

        float inv = (e > s) ? (1.f / den) : 0.f;
        v2f hg = pkfma(A, pksplat(inv), bo);
        hg = __builtin_elementwise_max(hg, pksplat(0.f));
        v2f hv = *(const v2f*)&hin[node * 128 + chb];
        *(v2f*)&hout[node * 128 + chb] = hv + hg;
    }
}

// ---------------- classifier ----------------

__global__ __launch_bounds__(256) void k_cls_lite(const float* __restrict__ emb, const float* __restrict__ Wc,
                                                  const float* __restrict__ bc, float* __restrict__ out_cls, int n) {
    int wid = threadIdx.x >> 6;
    int lane = threadIdx.x & 63;
    int node = blockIdx.x * 4 + wid;
    if (node >= n) return;
    float h0 = emb[(size_t)node * 128 + lane];
    float h1 = emb[(size_t)node * 128 + 64 + lane];
    float p[10];
#pragma unroll
    for (int k = 0; k < 10; k++) p[k] = h0 * Wc[lane * 10 + k] + h1 * Wc[(64 + lane) * 10 + k];
#pragma unroll
    for (int o = 32; o; o >>= 1) {
#pragma unroll
        for (int k = 0; k < 10; k++) p[k] += __shfl_xor(p[k], o, 64);
    }
    if (lane == 0) {
#pragma unroll
        for (int k = 0; k < 10; k++) out_cls[(size_t)node * 10 + k] = p[k] + bc[k];
    }
}

extern "C" void kernel_launch(void* const* d_in, const int* in_sizes, int n_in,
                              void* d_out, int out_size, void* d_ws, size_t ws_size,
                              hipStream_t stream) {
    const float* x         = (const float*)d_in[0];
    const int*   edge_idx  = (const int*)d_in[1];
    const float* edge_attr = (const float*)d_in[2];
    const float* Wp        = (const float*)d_in[3];
    const float* bp        = (const float*)d_in[4];
    const float* lng       = (const float*)d_in[5];
    const float* lnb       = (const float*)d_in[6];
    const float* Wl        = (const float*)d_in[7];
    const float* bl        = (const float*)d_in[8];
    const float* Wr        = (const float*)d_in[9];
    const float* br        = (const float*)d_in[10];
    const float* We        = (const float*)d_in[11];
    const float* att       = (const float*)d_in[12];
    const float* bout      = (const float*)d_in[13];
    const float* Wc        = (const float*)d_in[14];
    const float* bc        = (const float*)d_in[15];

    const int N = N_NODES, E = N_EDGES;

    char* w = (char*)d_ws;
    size_t used = 0;
    auto take = [&](size_t bytes) -> void* {
        void* p = (void*)(w + used);
        used += (bytes + 255) & ~(size_t)255;
        return p;
    };
    float* h      = (float*)take((size_t)N * 128 * 4);
    float* xl     = (float*)take((size_t)N * 128 * 4);
    float* xr     = (float*)take((size_t)N * 128 * 4);
    int*   indeg  = (int*)take((size_t)N * 4);
    int*   offs   = (int*)take((size_t)(N + 1) * 4);
    int*   cursor = (int*)take((size_t)N * 4);
    int*   bsum   = (int*)take(64 * 4);
    int*   seid   = (int*)take((size_t)E * 4);
    int*   ssrc   = (int*)take((size_t)E * 4);
    float* sea    = (float*)take((size_t)E * 16 * 4);
    bool sorted_ok = (used <= ws_size);

    float* out_cls = (float*)d_out;
    float* out_emb = (float*)d_out + (size_t)N * KCLS;

    const int* srcArr = edge_idx;
    const int* dstArr = edge_idx + E;

    (void)hipMemsetAsync(indeg, 0, (size_t)N * 4, stream);
    k_count<<<(E + 255) / 256, 256, 0, stream>>>(dstArr, indeg, E);
    int NB = (N + 1023) / 1024;
    k_scan_block<<<NB, 1024, 0, stream>>>(indeg, offs, bsum, N);
    k_scan_small<<<1, 64, 0, stream>>>(bsum, NB);
    k_scan_add<<<NB, 1024, 0, stream>>>(offs, bsum, cursor, N, E);
    if (sorted_ok)
        k_scatter_fused<<<(E + 255) / 256, 256, 0, stream>>>(srcArr, dstArr, edge_attr, cursor, ssrc, sea, E);
    else
        k_scatter<<<(E + 255) / 256, 256, 0, stream>>>(srcArr, dstArr, cursor, seid, ssrc, E);

    k_ln_gemm_first<<<(N + 31) / 32, 256, 0, stream>>>(
        x, Wp, bp, lng, lnb,
        Wl, bl, Wr, br, h, xl, xr, N);
    if (sorted_ok)
        k_gat_agg<true><<<AGG_BLOCKS, 256, 0, stream>>>(
            xl, xr, sea, offs, seid, ssrc, We, att, bout, h, h, N);
    else
        k_gat_agg<false><<<AGG_BLOCKS, 256, 0, stream>>>(
            xl, xr, edge_attr, offs, seid, ssrc, We, att, bout, h, h, N);

    k_ln_gemm<<<(N + 31) / 32, 256, 0, stream>>>(
        h, lng + 128, lnb + 128,
        Wl + (size_t)128 * 128, bl + 128,
        Wr + (size_t)128 * 128, br + 128,
        xl, xr, N);
    if (sorted_ok)
        k_gat_agg<true><<<AGG_BLOCKS, 256, 0, stream>>>(
            xl, xr, sea, offs, seid, ssrc,
            We + 16 * 128, att + 128, bout + 128, h, out_emb, N);
    else
        k_gat_agg<false><<<AGG_BLOCKS, 256, 0, stream>>>(
            xl, xr, edge_attr, offs, seid, ssrc,
            We + 16 * 128, att + 128, bout + 128, h, out_emb, N);

    k_cls_lite<<<(N + 3) / 4, 256, 0, stream>>>(out_emb, Wc, bc, out_cls, N);
}